// Round 6
// baseline (847.013 us; speedup 1.0000x reference)
//
#include <hip/hip_runtime.h>
#include <hip/hip_bf16.h>

// ---------------------------------------------------------------------------
// GNN regression: per timestep t: 3x GCNConv(relu) then edge-MLP head.
//   edge head: relu(concat(x[s],x[d],ea)@We + be) . Wg
//            = relu(u[s] + v[d] + ea@We_ea + be) . Wg   with u=x@We[:128], v=x@We[128:256]
//   GCN agg:   CSR-by-dst gather; matmul epilogue pre-scales rows by dinv;
//              gather fuses self-loop+bias+relu.
// NOTE: reference rebinds W1=W2 after t=0 (`W1 = W2; W1 = W1`).
// R2: edge_mlp LDS-staged + unrolled (375->124us).
// R3: matmul 64x128 reg-blocked; NEUTRAL (matmuls weren't the bottleneck).
// R4: bf16 gathered tables (hs/uv): FETCH halved exactly, edge_mlp 125->84us,
//     now VALU-issue-bound (VALUBusy 70%, hbm 28%).
// R5: all node tensors bf16 (x, A): gather reads rows 16 lanes x uint4
//     (4 rows/wave-load, 2x MLP), writes bf16; matmul reads bf16 X.
//     edge_mlp 4 channels/thread: ushort4 uv loads, float4 weights ->
//     per-edge wave-ops ~45 -> ~31 (loads 4->1, LDS 14->3.5 wave-insts).
// ---------------------------------------------------------------------------

#define BM 64
#define BK 32

__device__ __forceinline__ unsigned short f2bf(float f) {
    union { float f; unsigned int u; } v; v.f = f;
    unsigned int r = v.u + 0x7fffu + ((v.u >> 16) & 1u);  // RNE
    return (unsigned short)(r >> 16);
}
__device__ __forceinline__ float bf2f(unsigned short h) {
    union { unsigned int u; float f; } v; v.u = ((unsigned int)h) << 16;
    return v.f;
}
// unpack uint = 2 packed bf16 (lo = lower address/channel)
__device__ __forceinline__ void bf2x2(unsigned int u, float& lo, float& hi) {
    union { unsigned int x; float f; } a, b;
    a.x = u << 16; b.x = u & 0xffff0000u;
    lo = a.f; hi = b.f;
}
__device__ __forceinline__ unsigned int pk2bf(float lo, float hi) {
    return (unsigned int)f2bf(lo) | ((unsigned int)f2bf(hi) << 16);
}

__global__ void to_bf16(const float* __restrict__ in, unsigned short* __restrict__ out, int n4)
{
    int i = blockIdx.x * 256 + threadIdx.x;
    if (i < n4) {
        float4 v = ((const float4*)in)[i];
        ushort4 o;
        o.x = f2bf(v.x); o.y = f2bf(v.y); o.z = f2bf(v.z); o.w = f2bf(v.w);
        ((ushort4*)out)[i] = o;
    }
}

// out[r][c] = sum_k X[r][k]*W[k][c]; X bf16, W fp32, acc fp32, out bf16.
__global__ __launch_bounds__(256) void matmul128(
    const unsigned short* __restrict__ X, const float* __restrict__ W,
    unsigned short* __restrict__ out, const float* __restrict__ scale,
    int n_rows, int out_stride, int out_off)
{
    __shared__ float xs[BK][BM + 4];
    __shared__ float ws[BK][128 + 4];
    const int tid = threadIdx.x;
    const int r0  = blockIdx.x * BM;
    const int tr  = tid >> 5;   // 0..7  -> rows tr*8..tr*8+7
    const int tc  = tid & 31;   // cols tc*4..tc*4+3

    float acc[8][4] = {};

    for (int k0 = 0; k0 < 128; k0 += BK) {
        {
            int r  = tid & 63;
            int f0 = tid >> 6;            // 0..3
            int gr = r0 + r;
            #pragma unroll
            for (int it = 0; it < 2; ++it) {
                int f4 = f0 + it * 4;     // 0..7 -> k-offset f4*4
                ushort4 xv = make_ushort4(0, 0, 0, 0);
                if (gr < n_rows)
                    xv = *(const ushort4*)(X + (size_t)gr * 128 + k0 + f4 * 4);
                xs[f4 * 4 + 0][r] = bf2f(xv.x); xs[f4 * 4 + 1][r] = bf2f(xv.y);
                xs[f4 * 4 + 2][r] = bf2f(xv.z); xs[f4 * 4 + 3][r] = bf2f(xv.w);
            }
        }
        {
            int c4 = (tid & 31) * 4;
            int kb = tid >> 5;            // 0..7
            #pragma unroll
            for (int it = 0; it < 4; ++it) {
                int k = kb + it * 8;      // 0..31
                *(float4*)(&ws[k][c4]) =
                    *(const float4*)(W + (size_t)(k0 + k) * 128 + c4);
            }
        }
        __syncthreads();
        #pragma unroll
        for (int k = 0; k < BK; ++k) {
            float4 xv0 = *(const float4*)(&xs[k][tr * 8]);
            float4 xv1 = *(const float4*)(&xs[k][tr * 8 + 4]);
            float4 wv  = *(const float4*)(&ws[k][tc * 4]);
            float xr[8] = {xv0.x, xv0.y, xv0.z, xv0.w, xv1.x, xv1.y, xv1.z, xv1.w};
            #pragma unroll
            for (int i = 0; i < 8; ++i) {
                acc[i][0] = fmaf(xr[i], wv.x, acc[i][0]);
                acc[i][1] = fmaf(xr[i], wv.y, acc[i][1]);
                acc[i][2] = fmaf(xr[i], wv.z, acc[i][2]);
                acc[i][3] = fmaf(xr[i], wv.w, acc[i][3]);
            }
        }
        __syncthreads();
    }

    #pragma unroll
    for (int i = 0; i < 8; ++i) {
        int gr = r0 + tr * 8 + i;
        if (gr >= n_rows) continue;
        float s = scale ? scale[gr] : 1.0f;
        ushort4 o;
        o.x = f2bf(acc[i][0] * s); o.y = f2bf(acc[i][1] * s);
        o.z = f2bf(acc[i][2] * s); o.w = f2bf(acc[i][3] * s);
        *(ushort4*)(out + (size_t)gr * out_stride + out_off + tc * 4) = o;
    }
}

// x_new[n] = relu( dinv[n] * (hs[n] + sum_{e in in(n)} hs[src_e]) + b )
// 16 lanes/node, uint4 (16B = 8 bf16 ch) per lane -> 4 rows per wave-load.
__global__ __launch_bounds__(256) void gcn_gather(
    const unsigned short* __restrict__ hs, const int* __restrict__ csr_src,
    const int* __restrict__ offs, const int* __restrict__ counts,
    const float* __restrict__ dinv, const float* __restrict__ bias,
    unsigned short* __restrict__ xout, int n)
{
    int node = blockIdx.x * 16 + (threadIdx.x >> 4);
    if (node >= n) return;
    int lane = threadIdx.x & 15;
    int c8 = lane * 8;                 // channels c8..c8+7
    int off = offs[node];
    int cnt = counts[node];

    float a[8];
    {
        uint4 sv = *(const uint4*)(hs + (size_t)node * 128 + c8);  // self term
        bf2x2(sv.x, a[0], a[1]); bf2x2(sv.y, a[2], a[3]);
        bf2x2(sv.z, a[4], a[5]); bf2x2(sv.w, a[6], a[7]);
    }
    int j = 0;
    for (; j + 4 <= cnt; j += 4) {
        int s0 = csr_src[off + j + 0];
        int s1 = csr_src[off + j + 1];
        int s2 = csr_src[off + j + 2];
        int s3 = csr_src[off + j + 3];
        uint4 h0 = *(const uint4*)(hs + (size_t)s0 * 128 + c8);
        uint4 h1 = *(const uint4*)(hs + (size_t)s1 * 128 + c8);
        uint4 h2 = *(const uint4*)(hs + (size_t)s2 * 128 + c8);
        uint4 h3 = *(const uint4*)(hs + (size_t)s3 * 128 + c8);
        float lo, hi;
        bf2x2(h0.x, lo, hi); a[0] += lo; a[1] += hi;
        bf2x2(h0.y, lo, hi); a[2] += lo; a[3] += hi;
        bf2x2(h0.z, lo, hi); a[4] += lo; a[5] += hi;
        bf2x2(h0.w, lo, hi); a[6] += lo; a[7] += hi;
        bf2x2(h1.x, lo, hi); a[0] += lo; a[1] += hi;
        bf2x2(h1.y, lo, hi); a[2] += lo; a[3] += hi;
        bf2x2(h1.z, lo, hi); a[4] += lo; a[5] += hi;
        bf2x2(h1.w, lo, hi); a[6] += lo; a[7] += hi;
        bf2x2(h2.x, lo, hi); a[0] += lo; a[1] += hi;
        bf2x2(h2.y, lo, hi); a[2] += lo; a[3] += hi;
        bf2x2(h2.z, lo, hi); a[4] += lo; a[5] += hi;
        bf2x2(h2.w, lo, hi); a[6] += lo; a[7] += hi;
        bf2x2(h3.x, lo, hi); a[0] += lo; a[1] += hi;
        bf2x2(h3.y, lo, hi); a[2] += lo; a[3] += hi;
        bf2x2(h3.z, lo, hi); a[4] += lo; a[5] += hi;
        bf2x2(h3.w, lo, hi); a[6] += lo; a[7] += hi;
    }
    for (; j < cnt; ++j) {
        int s = csr_src[off + j];
        uint4 hv = *(const uint4*)(hs + (size_t)s * 128 + c8);
        float lo, hi;
        bf2x2(hv.x, lo, hi); a[0] += lo; a[1] += hi;
        bf2x2(hv.y, lo, hi); a[2] += lo; a[3] += hi;
        bf2x2(hv.z, lo, hi); a[4] += lo; a[5] += hi;
        bf2x2(hv.w, lo, hi); a[6] += lo; a[7] += hi;
    }
    float dn = dinv[node];
    float4 b0 = *(const float4*)(bias + c8);
    float4 b1 = *(const float4*)(bias + c8 + 4);
    float r0 = fmaxf(fmaf(a[0], dn, b0.x), 0.f);
    float r1 = fmaxf(fmaf(a[1], dn, b0.y), 0.f);
    float r2 = fmaxf(fmaf(a[2], dn, b0.z), 0.f);
    float r3 = fmaxf(fmaf(a[3], dn, b0.w), 0.f);
    float r4 = fmaxf(fmaf(a[4], dn, b1.x), 0.f);
    float r5 = fmaxf(fmaf(a[5], dn, b1.y), 0.f);
    float r6 = fmaxf(fmaf(a[6], dn, b1.z), 0.f);
    float r7 = fmaxf(fmaf(a[7], dn, b1.w), 0.f);
    uint4 o;
    o.x = pk2bf(r0, r1); o.y = pk2bf(r2, r3);
    o.z = pk2bf(r4, r5); o.w = pk2bf(r6, r7);
    *(uint4*)(xout + (size_t)node * 128 + c8) = o;
}

// acc += sum_e relu(u[src_e] + v[dst_e] + ea_e@We_ea + be) . Wg   (uv bf16)
// 4 channels/thread: 32 lanes/edge, ushort4 uv loads, float4 weights.
#define EM_CHUNK 256
__global__ __launch_bounds__(256) void edge_mlp(
    const unsigned short* __restrict__ uv, const int* __restrict__ src,
    const int* __restrict__ dst, const float* __restrict__ ea,
    const float* __restrict__ We_e, const float* __restrict__ be,
    const float* __restrict__ Wg, float* __restrict__ acc, int E)
{
    const int tid  = threadIdx.x;
    const int lane = tid & 31;       // channel quad: c4..c4+3
    const int g    = tid >> 5;       // group 0..7, one edge per group per step
    const int c4   = lane * 4;

    __shared__ float eas[EM_CHUNK * 7];
    __shared__ int   ss[EM_CHUNK];
    __shared__ int   ds[EM_CHUNK];
    __shared__ float red[256];

    float4 w[7];
    #pragma unroll
    for (int i = 0; i < 7; ++i)
        w[i] = *(const float4*)(We_e + i * 128 + c4);
    const float4 be4 = *(const float4*)(be + c4);
    const float4 wg4 = *(const float4*)(Wg + c4);

    float4 part = make_float4(0.f, 0.f, 0.f, 0.f);

    for (int base = blockIdx.x * EM_CHUNK; base < E; base += gridDim.x * EM_CHUNK) {
        const int nch = min(EM_CHUNK, E - base);
        for (int i = tid; i < nch * 7; i += 256)
            eas[i] = ea[(size_t)base * 7 + i];
        for (int i = tid; i < nch; i += 256) {
            ss[i] = src[base + i];
            ds[i] = dst[base + i];
        }
        __syncthreads();

        auto ev = [&](int j) {
            ushort4 us = *(const ushort4*)(uv + (size_t)ss[j] * 256 + c4);
            ushort4 vs = *(const ushort4*)(uv + (size_t)ds[j] * 256 + 128 + c4);
            const float* eav = &eas[j * 7];
            float4 val;
            val.x = bf2f(us.x) + bf2f(vs.x) + be4.x;
            val.y = bf2f(us.y) + bf2f(vs.y) + be4.y;
            val.z = bf2f(us.z) + bf2f(vs.z) + be4.z;
            val.w = bf2f(us.w) + bf2f(vs.w) + be4.w;
            #pragma unroll
            for (int i = 0; i < 7; ++i) {
                float e = eav[i];
                val.x = fmaf(e, w[i].x, val.x);
                val.y = fmaf(e, w[i].y, val.y);
                val.z = fmaf(e, w[i].z, val.z);
                val.w = fmaf(e, w[i].w, val.w);
            }
            part.x += fmaxf(val.x, 0.f);
            part.y += fmaxf(val.y, 0.f);
            part.z += fmaxf(val.z, 0.f);
            part.w += fmaxf(val.w, 0.f);
        };

        int j = g;
        for (; j + 32 <= nch; j += 32) {   // 4 edges/group/iter -> 8 loads in flight
            ev(j); ev(j + 8); ev(j + 16); ev(j + 24);
        }
        for (; j < nch; j += 8)
            ev(j);
        __syncthreads();
    }

    float p = part.x * wg4.x + part.y * wg4.y + part.z * wg4.z + part.w * wg4.w;
    red[tid] = p;
    __syncthreads();
    for (int s = 128; s > 0; s >>= 1) {
        if (tid < s) red[tid] += red[tid + s];
        __syncthreads();
    }
    if (tid == 0) atomicAdd(acc, red[0]);
}

// ---------------- CSR build ----------------
__global__ void count_edges(const int* __restrict__ dst, int* __restrict__ counts, int E)
{
    int e = blockIdx.x * 256 + threadIdx.x;
    if (e < E) atomicAdd(&counts[dst[e]], 1);
}

__global__ void compute_dinv(const int* __restrict__ counts, float* __restrict__ dinv, int n)
{
    int i = blockIdx.x * 256 + threadIdx.x;
    if (i < n) dinv[i] = rsqrtf((float)counts[i] + 1.0f);
}

__global__ void scan1(const int* __restrict__ counts, int* __restrict__ scanned,
                      int* __restrict__ btot, int n)
{
    __shared__ int sh[256];
    int i = blockIdx.x * 256 + threadIdx.x;
    int v = (i < n) ? counts[i] : 0;
    sh[threadIdx.x] = v;
    __syncthreads();
    for (int off = 1; off < 256; off <<= 1) {
        int t = (threadIdx.x >= off) ? sh[threadIdx.x - off] : 0;
        __syncthreads();
        sh[threadIdx.x] += t;
        __syncthreads();
    }
    if (i < n) scanned[i] = sh[threadIdx.x] - v;  // exclusive
    if (threadIdx.x == 255) btot[blockIdx.x] = sh[255];
}

__global__ void scan2(int* __restrict__ btot, int nb)
{
    __shared__ int sh[256];
    int v = (threadIdx.x < nb) ? btot[threadIdx.x] : 0;
    sh[threadIdx.x] = v;
    __syncthreads();
    for (int off = 1; off < 256; off <<= 1) {
        int t = (threadIdx.x >= off) ? sh[threadIdx.x - off] : 0;
        __syncthreads();
        sh[threadIdx.x] += t;
        __syncthreads();
    }
    if (threadIdx.x < nb) btot[threadIdx.x] = sh[threadIdx.x] - v;  // exclusive
}

__global__ void scan3(const int* __restrict__ scanned, const int* __restrict__ btot,
                      int* __restrict__ offs, int* __restrict__ cursor, int n)
{
    int i = blockIdx.x * 256 + threadIdx.x;
    if (i < n) {
        int o = scanned[i] + btot[blockIdx.x];
        offs[i] = o;
        cursor[i] = o;
    }
}

__global__ void fill_csr(const int* __restrict__ src, const int* __restrict__ dst,
                         int* __restrict__ cursor, int* __restrict__ csr_src, int E)
{
    int e = blockIdx.x * 256 + threadIdx.x;
    if (e < E) {
        int slot = atomicAdd(&cursor[dst[e]], 1);
        csr_src[slot] = src[e];
    }
}

__global__ void write_out(const float* __restrict__ acc, const float* __restrict__ bg,
                          float* __restrict__ out, float invE, int T)
{
    int t = threadIdx.x;
    if (t < T) out[t] = acc[t] * invE + bg[0];
}

// ---------------------------------------------------------------------------

extern "C" void kernel_launch(void* const* d_in, const int* in_sizes, int n_in,
                              void* d_out, int out_size, void* d_ws, size_t ws_size,
                              hipStream_t stream)
{
    const float* x   = (const float*)d_in[0];
    const int*  eidx = (const int*)d_in[1];
    const float* ea  = (const float*)d_in[2];
    const float* W1  = (const float*)d_in[3];
    const float* b1  = (const float*)d_in[4];
    const float* W2  = (const float*)d_in[5];
    const float* b2  = (const float*)d_in[6];
    const float* W3  = (const float*)d_in[7];
    const float* b3  = (const float*)d_in[8];
    const float* We  = (const float*)d_in[9];
    const float* be  = (const float*)d_in[10];
    const float* Wg  = (const float*)d_in[11];
    const float* bg  = (const float*)d_in[12];

    const int N = in_sizes[0] / 128;
    const int E = in_sizes[1] / 2;
    const int T = in_sizes[2] / (E * 7);
    const int* src = eidx;
    const int* dst = eidx + E;

    char* wsp = (char*)d_ws;
    auto alloc = [&](size_t bytes) -> char* {
        char* p = wsp;
        wsp += (bytes + 255) / 256 * 256;
        return p;
    };
    int*   counts  = (int*)alloc((size_t)N * 4);
    int*   offs    = (int*)alloc((size_t)N * 4);
    int*   cursor  = (int*)alloc((size_t)N * 4);
    int*   scanned = (int*)alloc((size_t)N * 4);
    int*   btot    = (int*)alloc(1024);
    int*   csr_src = (int*)alloc((size_t)E * 4);
    float* dinv    = (float*)alloc((size_t)N * 4);
    float* acc     = (float*)alloc(256);
    unsigned short* X0 = (unsigned short*)alloc((size_t)N * 128 * 2);  // x in bf16
    unsigned short* A  = (unsigned short*)alloc((size_t)N * 128 * 2);  // evolving x (bf16)
    unsigned short* B  = (unsigned short*)alloc((size_t)N * 256 * 2);  // hs/uv (bf16)

    hipMemsetAsync(counts, 0, (size_t)N * 4, stream);
    hipMemsetAsync(acc, 0, (size_t)T * 4, stream);

    to_bf16<<<(N * 128 / 4 + 255) / 256, 256, 0, stream>>>(x, X0, N * 128 / 4);

    count_edges<<<(E + 255) / 256, 256, 0, stream>>>(dst, counts, E);
    compute_dinv<<<(N + 255) / 256, 256, 0, stream>>>(counts, dinv, N);
    const int nb = (N + 255) / 256;
    scan1<<<nb, 256, 0, stream>>>(counts, scanned, btot, N);
    scan2<<<1, 256, 0, stream>>>(btot, nb);
    scan3<<<nb, 256, 0, stream>>>(scanned, btot, offs, cursor, N);
    fill_csr<<<(E + 255) / 256, 256, 0, stream>>>(src, dst, cursor, csr_src, E);

    const int mmb = (N + BM - 1) / BM;
    const int ngb = (N + 15) / 16;
    const int emb = (E + EM_CHUNK - 1) / EM_CHUNK;

    for (int t = 0; t < T; ++t) {
        const unsigned short* xin = (t == 0) ? X0 : A;
        const float* Wc1 = (t == 0) ? W1 : W2;  // reference rebinds W1=W2 after t=0
        matmul128<<<mmb, 256, 0, stream>>>(xin, Wc1, B, dinv, N, 128, 0);
        gcn_gather<<<ngb, 256, 0, stream>>>(B, csr_src, offs, counts, dinv, b1, A, N);
        matmul128<<<mmb, 256, 0, stream>>>(A, W2, B, dinv, N, 128, 0);
        gcn_gather<<<ngb, 256, 0, stream>>>(B, csr_src, offs, counts, dinv, b2, A, N);
        matmul128<<<mmb, 256, 0, stream>>>(A, W3, B, dinv, N, 128, 0);
        gcn_gather<<<ngb, 256, 0, stream>>>(B, csr_src, offs, counts, dinv, b3, A, N);
        matmul128<<<mmb, 256, 0, stream>>>(A, We, B, nullptr, N, 256, 0);
        matmul128<<<mmb, 256, 0, stream>>>(A, We + 128 * 128, B, nullptr, N, 256, 128);
        edge_mlp<<<emb, 256, 0, stream>>>(B, src, dst, ea + (size_t)t * E * 7,
                                          We + 256 * 128, be, Wg, acc + t, E);
    }
    write_out<<<1, 64, 0, stream>>>(acc, bg, (float*)d_out, 1.0f / (float)E, T);
}

// Round 7
// 771.070 us; speedup vs baseline: 1.0985x; 1.0985x over previous
//
#include <hip/hip_runtime.h>
#include <hip/hip_bf16.h>

// ---------------------------------------------------------------------------
// GNN regression: per timestep t: 3x GCNConv(relu) then edge-MLP head.
//   edge head: relu(concat(x[s],x[d],ea)@We + be) . Wg
//            = relu(u[s] + v[d] + ea@We_ea + be) . Wg   with u=x@We[:128], v=x@We[128:256]
//   GCN agg:   CSR-by-dst gather; matmul epilogue pre-scales rows by dinv;
//              gather fuses self-loop+bias+relu.
// NOTE: reference rebinds W1=W2 after t=0 (`W1 = W2; W1 = W1`).
// R2: edge_mlp LDS-staged + unrolled (375->124us).
// R3: matmul 64x128 reg-blocked; NEUTRAL.
// R4: bf16 gathered tables: FETCH halved, edge_mlp 125->84us.
// R5: all node tensors bf16; gather 16Bx16-lane rows; edge_mlp 4ch/thread.
// R6: edge_mlp VALU cut was time-neutral -> it's request/latency-bound at the
//     per-XCD-table-copy FETCH floor (184MB ~= 8 XCD x 25.6MB). New: matmuls
//     moved to MFMA bf16 (16x16x32, m89/m91 layouts), W converted to bf16
//     once per launch (We_ea row block stays fp32 in edge_mlp).
// ---------------------------------------------------------------------------

__device__ __forceinline__ unsigned short f2bf(float f) {
    union { float f; unsigned int u; } v; v.f = f;
    unsigned int r = v.u + 0x7fffu + ((v.u >> 16) & 1u);  // RNE
    return (unsigned short)(r >> 16);
}
__device__ __forceinline__ float bf2f(unsigned short h) {
    union { unsigned int u; float f; } v; v.u = ((unsigned int)h) << 16;
    return v.f;
}
__device__ __forceinline__ void bf2x2(unsigned int u, float& lo, float& hi) {
    union { unsigned int x; float f; } a, b;
    a.x = u << 16; b.x = u & 0xffff0000u;
    lo = a.f; hi = b.f;
}
__device__ __forceinline__ unsigned int pk2bf(float lo, float hi) {
    return (unsigned int)f2bf(lo) | ((unsigned int)f2bf(hi) << 16);
}

__global__ void to_bf16(const float* __restrict__ in, unsigned short* __restrict__ out, int n4)
{
    int i = blockIdx.x * 256 + threadIdx.x;
    if (i < n4) {
        float4 v = ((const float4*)in)[i];
        ushort4 o;
        o.x = f2bf(v.x); o.y = f2bf(v.y); o.z = f2bf(v.z); o.w = f2bf(v.w);
        ((ushort4*)out)[i] = o;
    }
}

// ---------------- MFMA matmul: out[r][c] = sum_k X[r][k] * W[k][c] ----------
// X bf16 [n,128], Wb bf16 [128,128] row-major; out bf16, optional row scale.
// Block: 256 thr (4 waves), 64 rows. Wave w: rows w*16..w*16+15, all 128 cols
// as 8 16-wide tiles. A-frag from global (rows contiguous); B-frag from LDS
// (W staged transposed, row stride padded to 136 to break bank aliasing).
// Layouts (cdna_hip_programming.md §3, m89/m91): A[m=lane&15][k=quad*8+j];
// C/D col=lane&15, row=quad*4+reg.
#define PADK 136
typedef __attribute__((ext_vector_type(8))) short bf16x8;
typedef __attribute__((ext_vector_type(4))) float f32x4;

__global__ __launch_bounds__(256) void mfma_matmul(
    const unsigned short* __restrict__ X, const unsigned short* __restrict__ Wb,
    unsigned short* __restrict__ out, const float* __restrict__ scale,
    int n_rows, int out_stride, int out_off)
{
    __shared__ unsigned short wt[128 * PADK];   // W^T: wt[c*PADK + k]

    // stage transpose: Wb[k][c] -> wt[c][k]
    for (int i = threadIdx.x; i < 128 * 32; i += 256) {
        int k = i >> 5;
        int c = (i & 31) * 4;
        ushort4 v = *(const ushort4*)(Wb + k * 128 + c);
        wt[(c + 0) * PADK + k] = v.x;
        wt[(c + 1) * PADK + k] = v.y;
        wt[(c + 2) * PADK + k] = v.z;
        wt[(c + 3) * PADK + k] = v.w;
    }
    __syncthreads();

    const int wave = threadIdx.x >> 6;
    const int lane = threadIdx.x & 63;
    const int m = lane & 15;        // row-in-tile (A) / col-in-tile (C/D)
    const int q = lane >> 4;        // quad -> k-offset q*8
    const int r = blockIdx.x * 64 + wave * 16 + m;   // A-frag source row
    const bool rv = r < n_rows;

    f32x4 acc[8];
    #pragma unroll
    for (int i = 0; i < 8; ++i) acc[i] = (f32x4){0.f, 0.f, 0.f, 0.f};

    #pragma unroll
    for (int k0 = 0; k0 < 128; k0 += 32) {
        bf16x8 a = {};
        if (rv) a = *(const bf16x8*)(X + (size_t)r * 128 + k0 + q * 8);
        #pragma unroll
        for (int ct = 0; ct < 8; ++ct) {
            int c = ct * 16 + m;
            bf16x8 b = *(const bf16x8*)(&wt[c * PADK + k0 + q * 8]);
            acc[ct] = __builtin_amdgcn_mfma_f32_16x16x32_bf16(a, b, acc[ct], 0, 0, 0);
        }
    }

    #pragma unroll
    for (int reg = 0; reg < 4; ++reg) {
        int gr = blockIdx.x * 64 + wave * 16 + q * 4 + reg;
        if (gr >= n_rows) continue;
        float s = scale ? scale[gr] : 1.0f;
        #pragma unroll
        for (int ct = 0; ct < 8; ++ct) {
            out[(size_t)gr * out_stride + out_off + ct * 16 + m] =
                f2bf(acc[ct][reg] * s);
        }
    }
}

// x_new[n] = relu( dinv[n] * (hs[n] + sum_{e in in(n)} hs[src_e]) + b )
// 16 lanes/node, uint4 (16B = 8 bf16 ch) per lane -> 4 rows per wave-load.
__global__ __launch_bounds__(256) void gcn_gather(
    const unsigned short* __restrict__ hs, const int* __restrict__ csr_src,
    const int* __restrict__ offs, const int* __restrict__ counts,
    const float* __restrict__ dinv, const float* __restrict__ bias,
    unsigned short* __restrict__ xout, int n)
{
    int node = blockIdx.x * 16 + (threadIdx.x >> 4);
    if (node >= n) return;
    int lane = threadIdx.x & 15;
    int c8 = lane * 8;
    int off = offs[node];
    int cnt = counts[node];

    float a[8];
    {
        uint4 sv = *(const uint4*)(hs + (size_t)node * 128 + c8);
        bf2x2(sv.x, a[0], a[1]); bf2x2(sv.y, a[2], a[3]);
        bf2x2(sv.z, a[4], a[5]); bf2x2(sv.w, a[6], a[7]);
    }
    int j = 0;
    for (; j + 4 <= cnt; j += 4) {
        int s0 = csr_src[off + j + 0];
        int s1 = csr_src[off + j + 1];
        int s2 = csr_src[off + j + 2];
        int s3 = csr_src[off + j + 3];
        uint4 h0 = *(const uint4*)(hs + (size_t)s0 * 128 + c8);
        uint4 h1 = *(const uint4*)(hs + (size_t)s1 * 128 + c8);
        uint4 h2 = *(const uint4*)(hs + (size_t)s2 * 128 + c8);
        uint4 h3 = *(const uint4*)(hs + (size_t)s3 * 128 + c8);
        float lo, hi;
        bf2x2(h0.x, lo, hi); a[0] += lo; a[1] += hi;
        bf2x2(h0.y, lo, hi); a[2] += lo; a[3] += hi;
        bf2x2(h0.z, lo, hi); a[4] += lo; a[5] += hi;
        bf2x2(h0.w, lo, hi); a[6] += lo; a[7] += hi;
        bf2x2(h1.x, lo, hi); a[0] += lo; a[1] += hi;
        bf2x2(h1.y, lo, hi); a[2] += lo; a[3] += hi;
        bf2x2(h1.z, lo, hi); a[4] += lo; a[5] += hi;
        bf2x2(h1.w, lo, hi); a[6] += lo; a[7] += hi;
        bf2x2(h2.x, lo, hi); a[0] += lo; a[1] += hi;
        bf2x2(h2.y, lo, hi); a[2] += lo; a[3] += hi;
        bf2x2(h2.z, lo, hi); a[4] += lo; a[5] += hi;
        bf2x2(h2.w, lo, hi); a[6] += lo; a[7] += hi;
        bf2x2(h3.x, lo, hi); a[0] += lo; a[1] += hi;
        bf2x2(h3.y, lo, hi); a[2] += lo; a[3] += hi;
        bf2x2(h3.z, lo, hi); a[4] += lo; a[5] += hi;
        bf2x2(h3.w, lo, hi); a[6] += lo; a[7] += hi;
    }
    for (; j < cnt; ++j) {
        int s = csr_src[off + j];
        uint4 hv = *(const uint4*)(hs + (size_t)s * 128 + c8);
        float lo, hi;
        bf2x2(hv.x, lo, hi); a[0] += lo; a[1] += hi;
        bf2x2(hv.y, lo, hi); a[2] += lo; a[3] += hi;
        bf2x2(hv.z, lo, hi); a[4] += lo; a[5] += hi;
        bf2x2(hv.w, lo, hi); a[6] += lo; a[7] += hi;
    }
    float dn = dinv[node];
    float4 b0 = *(const float4*)(bias + c8);
    float4 b1 = *(const float4*)(bias + c8 + 4);
    float r0 = fmaxf(fmaf(a[0], dn, b0.x), 0.f);
    float r1 = fmaxf(fmaf(a[1], dn, b0.y), 0.f);
    float r2 = fmaxf(fmaf(a[2], dn, b0.z), 0.f);
    float r3 = fmaxf(fmaf(a[3], dn, b0.w), 0.f);
    float r4 = fmaxf(fmaf(a[4], dn, b1.x), 0.f);
    float r5 = fmaxf(fmaf(a[5], dn, b1.y), 0.f);
    float r6 = fmaxf(fmaf(a[6], dn, b1.z), 0.f);
    float r7 = fmaxf(fmaf(a[7], dn, b1.w), 0.f);
    uint4 o;
    o.x = pk2bf(r0, r1); o.y = pk2bf(r2, r3);
    o.z = pk2bf(r4, r5); o.w = pk2bf(r6, r7);
    *(uint4*)(xout + (size_t)node * 128 + c8) = o;
}

// acc += sum_e relu(u[src_e] + v[dst_e] + ea_e@We_ea + be) . Wg   (uv bf16)
#define EM_CHUNK 256
__global__ __launch_bounds__(256) void edge_mlp(
    const unsigned short* __restrict__ uv, const int* __restrict__ src,
    const int* __restrict__ dst, const float* __restrict__ ea,
    const float* __restrict__ We_e, const float* __restrict__ be,
    const float* __restrict__ Wg, float* __restrict__ acc, int E)
{
    const int tid  = threadIdx.x;
    const int lane = tid & 31;
    const int g    = tid >> 5;
    const int c4   = lane * 4;

    __shared__ float eas[EM_CHUNK * 7];
    __shared__ int   ss[EM_CHUNK];
    __shared__ int   ds[EM_CHUNK];
    __shared__ float red[256];

    float4 w[7];
    #pragma unroll
    for (int i = 0; i < 7; ++i)
        w[i] = *(const float4*)(We_e + i * 128 + c4);
    const float4 be4 = *(const float4*)(be + c4);
    const float4 wg4 = *(const float4*)(Wg + c4);

    float4 part = make_float4(0.f, 0.f, 0.f, 0.f);

    for (int base = blockIdx.x * EM_CHUNK; base < E; base += gridDim.x * EM_CHUNK) {
        const int nch = min(EM_CHUNK, E - base);
        for (int i = tid; i < nch * 7; i += 256)
            eas[i] = ea[(size_t)base * 7 + i];
        for (int i = tid; i < nch; i += 256) {
            ss[i] = src[base + i];
            ds[i] = dst[base + i];
        }
        __syncthreads();

        auto ev = [&](int j) {
            ushort4 us = *(const ushort4*)(uv + (size_t)ss[j] * 256 + c4);
            ushort4 vs = *(const ushort4*)(uv + (size_t)ds[j] * 256 + 128 + c4);
            const float* eav = &eas[j * 7];
            float4 val;
            val.x = bf2f(us.x) + bf2f(vs.x) + be4.x;
            val.y = bf2f(us.y) + bf2f(vs.y) + be4.y;
            val.z = bf2f(us.z) + bf2f(vs.z) + be4.z;
            val.w = bf2f(us.w) + bf2f(vs.w) + be4.w;
            #pragma unroll
            for (int i = 0; i < 7; ++i) {
                float e = eav[i];
                val.x = fmaf(e, w[i].x, val.x);
                val.y = fmaf(e, w[i].y, val.y);
                val.z = fmaf(e, w[i].z, val.z);
                val.w = fmaf(e, w[i].w, val.w);
            }
            part.x += fmaxf(val.x, 0.f);
            part.y += fmaxf(val.y, 0.f);
            part.z += fmaxf(val.z, 0.f);
            part.w += fmaxf(val.w, 0.f);
        };

        int j = g;
        for (; j + 32 <= nch; j += 32) {
            ev(j); ev(j + 8); ev(j + 16); ev(j + 24);
        }
        for (; j < nch; j += 8)
            ev(j);
        __syncthreads();
    }

    float p = part.x * wg4.x + part.y * wg4.y + part.z * wg4.z + part.w * wg4.w;
    red[tid] = p;
    __syncthreads();
    for (int s = 128; s > 0; s >>= 1) {
        if (tid < s) red[tid] += red[tid + s];
        __syncthreads();
    }
    if (tid == 0) atomicAdd(acc, red[0]);
}

// ---------------- CSR build ----------------
__global__ void count_edges(const int* __restrict__ dst, int* __restrict__ counts, int E)
{
    int e = blockIdx.x * 256 + threadIdx.x;
    if (e < E) atomicAdd(&counts[dst[e]], 1);
}

__global__ void compute_dinv(const int* __restrict__ counts, float* __restrict__ dinv, int n)
{
    int i = blockIdx.x * 256 + threadIdx.x;
    if (i < n) dinv[i] = rsqrtf((float)counts[i] + 1.0f);
}

__global__ void scan1(const int* __restrict__ counts, int* __restrict__ scanned,
                      int* __restrict__ btot, int n)
{
    __shared__ int sh[256];
    int i = blockIdx.x * 256 + threadIdx.x;
    int v = (i < n) ? counts[i] : 0;
    sh[threadIdx.x] = v;
    __syncthreads();
    for (int off = 1; off < 256; off <<= 1) {
        int t = (threadIdx.x >= off) ? sh[threadIdx.x - off] : 0;
        __syncthreads();
        sh[threadIdx.x] += t;
        __syncthreads();
    }
    if (i < n) scanned[i] = sh[threadIdx.x] - v;  // exclusive
    if (threadIdx.x == 255) btot[blockIdx.x] = sh[255];
}

__global__ void scan2(int* __restrict__ btot, int nb)
{
    __shared__ int sh[256];
    int v = (threadIdx.x < nb) ? btot[threadIdx.x] : 0;
    sh[threadIdx.x] = v;
    __syncthreads();
    for (int off = 1; off < 256; off <<= 1) {
        int t = (threadIdx.x >= off) ? sh[threadIdx.x - off] : 0;
        __syncthreads();
        sh[threadIdx.x] += t;
        __syncthreads();
    }
    if (threadIdx.x < nb) btot[threadIdx.x] = sh[threadIdx.x] - v;  // exclusive
}

__global__ void scan3(const int* __restrict__ scanned, const int* __restrict__ btot,
                      int* __restrict__ offs, int* __restrict__ cursor, int n)
{
    int i = blockIdx.x * 256 + threadIdx.x;
    if (i < n) {
        int o = scanned[i] + btot[blockIdx.x];
        offs[i] = o;
        cursor[i] = o;
    }
}

__global__ void fill_csr(const int* __restrict__ src, const int* __restrict__ dst,
                         int* __restrict__ cursor, int* __restrict__ csr_src, int E)
{
    int e = blockIdx.x * 256 + threadIdx.x;
    if (e < E) {
        int slot = atomicAdd(&cursor[dst[e]], 1);
        csr_src[slot] = src[e];
    }
}

__global__ void write_out(const float* __restrict__ acc, const float* __restrict__ bg,
                          float* __restrict__ out, float invE, int T)
{
    int t = threadIdx.x;
    if (t < T) out[t] = acc[t] * invE + bg[0];
}

// ---------------------------------------------------------------------------

extern "C" void kernel_launch(void* const* d_in, const int* in_sizes, int n_in,
                              void* d_out, int out_size, void* d_ws, size_t ws_size,
                              hipStream_t stream)
{
    const float* x   = (const float*)d_in[0];
    const int*  eidx = (const int*)d_in[1];
    const float* ea  = (const float*)d_in[2];
    const float* W1  = (const float*)d_in[3];
    const float* b1  = (const float*)d_in[4];
    const float* W2  = (const float*)d_in[5];
    const float* b2  = (const float*)d_in[6];
    const float* W3  = (const float*)d_in[7];
    const float* b3  = (const float*)d_in[8];
    const float* We  = (const float*)d_in[9];
    const float* be  = (const float*)d_in[10];
    const float* Wg  = (const float*)d_in[11];
    const float* bg  = (const float*)d_in[12];

    const int N = in_sizes[0] / 128;
    const int E = in_sizes[1] / 2;
    const int T = in_sizes[2] / (E * 7);
    const int* src = eidx;
    const int* dst = eidx + E;

    char* wsp = (char*)d_ws;
    auto alloc = [&](size_t bytes) -> char* {
        char* p = wsp;
        wsp += (bytes + 255) / 256 * 256;
        return p;
    };
    int*   counts  = (int*)alloc((size_t)N * 4);
    int*   offs    = (int*)alloc((size_t)N * 4);
    int*   cursor  = (int*)alloc((size_t)N * 4);
    int*   scanned = (int*)alloc((size_t)N * 4);
    int*   btot    = (int*)alloc(1024);
    int*   csr_src = (int*)alloc((size_t)E * 4);
    float* dinv    = (float*)alloc((size_t)N * 4);
    float* acc     = (float*)alloc(256);
    unsigned short* X0 = (unsigned short*)alloc((size_t)N * 128 * 2);  // x bf16
    unsigned short* A  = (unsigned short*)alloc((size_t)N * 128 * 2);  // evolving x
    unsigned short* B  = (unsigned short*)alloc((size_t)N * 256 * 2);  // hs/uv
    unsigned short* W1b = (unsigned short*)alloc(128 * 128 * 2);
    unsigned short* W2b = (unsigned short*)alloc(128 * 128 * 2);
    unsigned short* W3b = (unsigned short*)alloc(128 * 128 * 2);
    unsigned short* Wuvb = (unsigned short*)alloc(256 * 128 * 2);      // We rows 0..255

    hipMemsetAsync(counts, 0, (size_t)N * 4, stream);
    hipMemsetAsync(acc, 0, (size_t)T * 4, stream);

    to_bf16<<<(N * 128 / 4 + 255) / 256, 256, 0, stream>>>(x, X0, N * 128 / 4);
    to_bf16<<<16, 256, 0, stream>>>(W1, W1b, 128 * 128 / 4);
    to_bf16<<<16, 256, 0, stream>>>(W2, W2b, 128 * 128 / 4);
    to_bf16<<<16, 256, 0, stream>>>(W3, W3b, 128 * 128 / 4);
    to_bf16<<<32, 256, 0, stream>>>(We, Wuvb, 256 * 128 / 4);

    count_edges<<<(E + 255) / 256, 256, 0, stream>>>(dst, counts, E);
    compute_dinv<<<(N + 255) / 256, 256, 0, stream>>>(counts, dinv, N);
    const int nb = (N + 255) / 256;
    scan1<<<nb, 256, 0, stream>>>(counts, scanned, btot, N);
    scan2<<<1, 256, 0, stream>>>(btot, nb);
    scan3<<<nb, 256, 0, stream>>>(scanned, btot, offs, cursor, N);
    fill_csr<<<(E + 255) / 256, 256, 0, stream>>>(src, dst, cursor, csr_src, E);

    const int mmb = (N + 63) / 64;
    const int ngb = (N + 15) / 16;
    const int emb = (E + EM_CHUNK - 1) / EM_CHUNK;

    for (int t = 0; t < T; ++t) {
        const unsigned short* xin = (t == 0) ? X0 : A;
        const unsigned short* Wc1 = (t == 0) ? W1b : W2b;  // ref rebinds W1=W2 after t=0
        mfma_matmul<<<mmb, 256, 0, stream>>>(xin, Wc1, B, dinv, N, 128, 0);
        gcn_gather<<<ngb, 256, 0, stream>>>(B, csr_src, offs, counts, dinv, b1, A, N);
        mfma_matmul<<<mmb, 256, 0, stream>>>(A, W2b, B, dinv, N, 128, 0);
        gcn_gather<<<ngb, 256, 0, stream>>>(B, csr_src, offs, counts, dinv, b2, A, N);
        mfma_matmul<<<mmb, 256, 0, stream>>>(A, W3b, B, dinv, N, 128, 0);
        gcn_gather<<<ngb, 256, 0, stream>>>(B, csr_src, offs, counts, dinv, b3, A, N);
        mfma_matmul<<<mmb, 256, 0, stream>>>(A, Wuvb, B, nullptr, N, 256, 0);
        mfma_matmul<<<mmb, 256, 0, stream>>>(A, Wuvb + 128 * 128, B, nullptr, N, 256, 128);
        edge_mlp<<<emb, 256, 0, stream>>>(B, src, dst, ea + (size_t)t * E * 7,
                                          We + 256 * 128, be, Wg, acc + t, E);
    }
    write_out<<<1, 64, 0, stream>>>(acc, bg, (float*)d_out, 1.0f / (float)E, T);
}

// Round 8
// 680.223 us; speedup vs baseline: 1.2452x; 1.1336x over previous
//
#include <hip/hip_runtime.h>
#include <hip/hip_bf16.h>

// ---------------------------------------------------------------------------
// GNN regression: per timestep t: 3x GCNConv(relu) then edge-MLP head.
//   edge head: relu(concat(x[s],x[d],ea)@We + be) . Wg
//            = relu(u[s] + v[d] + ea@We_ea + be) . Wg   with u=x@We[:128], v=x@We[128:256]
//   GCN agg:   CSR-by-dst gather; matmul epilogue pre-scales rows by dinv;
//              gather fuses self-loop+bias+relu.
// NOTE: reference rebinds W1=W2 after t=0 (`W1 = W2; W1 = W1`).
// R2: edge_mlp LDS-staged + unrolled (375->124us).
// R3: matmul reg-blocked: NEUTRAL. R4: bf16 tables (125->84us edge).
// R5: bf16 node tensors. R6: edge_mlp is request/latency-bound at the
//     per-XCD FETCH floor; MFMA matmuls (R7: 847->771us, ~7.5us/matmul saved).
// R8: fp8(e4m3, HW cvt) storage for the two RANDOM-GATHERED tables only
//     (hs 128B rows, uv 256B rows). fp32 accumulate; A stays bf16; ea-path
//     stays fp32. Output err est ~5e-5 vs 1.1e-3 threshold. Gather: 8
//     lanes/node x uint4 = 16ch/lane, 8 rows per wave-load.
// ---------------------------------------------------------------------------

typedef __attribute__((ext_vector_type(8))) short bf16x8;
typedef __attribute__((ext_vector_type(4))) float f32x4;
typedef __attribute__((ext_vector_type(2))) float f32x2;

__device__ __forceinline__ unsigned short f2bf(float f) {
    union { float f; unsigned int u; } v; v.f = f;
    unsigned int r = v.u + 0x7fffu + ((v.u >> 16) & 1u);  // RNE
    return (unsigned short)(r >> 16);
}
__device__ __forceinline__ float bf2f(unsigned short h) {
    union { unsigned int u; float f; } v; v.u = ((unsigned int)h) << 16;
    return v.f;
}
__device__ __forceinline__ unsigned int pk2bf(float lo, float hi) {
    return (unsigned int)f2bf(lo) | ((unsigned int)f2bf(hi) << 16);
}
// fp8 e4m3 (OCP on gfx950) via HW converts
__device__ __forceinline__ unsigned char f2fp8(float f) {
    return (unsigned char)(__builtin_amdgcn_cvt_pk_fp8_f32(f, f, 0, false) & 0xff);
}
__device__ __forceinline__ void fp8x4(unsigned int u, float* o) {
    f32x2 lo = __builtin_amdgcn_cvt_pk_f32_fp8(u, false);
    f32x2 hi = __builtin_amdgcn_cvt_pk_f32_fp8(u, true);
    o[0] = lo[0]; o[1] = lo[1]; o[2] = hi[0]; o[3] = hi[1];
}
__device__ __forceinline__ void de16add(uint4 v, float* a) {
    float t[4];
    fp8x4(v.x, t); a[0]+=t[0]; a[1]+=t[1]; a[2]+=t[2]; a[3]+=t[3];
    fp8x4(v.y, t); a[4]+=t[0]; a[5]+=t[1]; a[6]+=t[2]; a[7]+=t[3];
    fp8x4(v.z, t); a[8]+=t[0]; a[9]+=t[1]; a[10]+=t[2]; a[11]+=t[3];
    fp8x4(v.w, t); a[12]+=t[0]; a[13]+=t[1]; a[14]+=t[2]; a[15]+=t[3];
}

__global__ void to_bf16(const float* __restrict__ in, unsigned short* __restrict__ out, int n4)
{
    int i = blockIdx.x * 256 + threadIdx.x;
    if (i < n4) {
        float4 v = ((const float4*)in)[i];
        ushort4 o;
        o.x = f2bf(v.x); o.y = f2bf(v.y); o.z = f2bf(v.z); o.w = f2bf(v.w);
        ((ushort4*)out)[i] = o;
    }
}

// ---------------- MFMA matmul: out[r][c] = sum_k X[r][k]*W[k][c] ------------
// X bf16 [n,128], Wb bf16 [128,128]; out fp8 e4m3 (byte) rows, optional scale.
// Layouts verified (m89/m91): A[m=lane&15][k=quad*8+j]; C/D col=lane&15,
// row=quad*4+reg. W staged transposed in LDS (PADK stride).
#define PADK 136
__global__ __launch_bounds__(256) void mfma_matmul(
    const unsigned short* __restrict__ X, const unsigned short* __restrict__ Wb,
    unsigned char* __restrict__ out, const float* __restrict__ scale,
    int n_rows, int out_stride, int out_off)
{
    __shared__ unsigned short wt[128 * PADK];   // W^T: wt[c*PADK + k]

    for (int i = threadIdx.x; i < 128 * 32; i += 256) {
        int k = i >> 5;
        int c = (i & 31) * 4;
        ushort4 v = *(const ushort4*)(Wb + k * 128 + c);
        wt[(c + 0) * PADK + k] = v.x;
        wt[(c + 1) * PADK + k] = v.y;
        wt[(c + 2) * PADK + k] = v.z;
        wt[(c + 3) * PADK + k] = v.w;
    }
    __syncthreads();

    const int wave = threadIdx.x >> 6;
    const int lane = threadIdx.x & 63;
    const int m = lane & 15;
    const int q = lane >> 4;
    const int r = blockIdx.x * 64 + wave * 16 + m;
    const bool rv = r < n_rows;

    f32x4 acc[8];
    #pragma unroll
    for (int i = 0; i < 8; ++i) acc[i] = (f32x4){0.f, 0.f, 0.f, 0.f};

    #pragma unroll
    for (int k0 = 0; k0 < 128; k0 += 32) {
        bf16x8 a = {};
        if (rv) a = *(const bf16x8*)(X + (size_t)r * 128 + k0 + q * 8);
        #pragma unroll
        for (int ct = 0; ct < 8; ++ct) {
            int c = ct * 16 + m;
            bf16x8 b = *(const bf16x8*)(&wt[c * PADK + k0 + q * 8]);
            acc[ct] = __builtin_amdgcn_mfma_f32_16x16x32_bf16(a, b, acc[ct], 0, 0, 0);
        }
    }

    #pragma unroll
    for (int reg = 0; reg < 4; ++reg) {
        int gr = blockIdx.x * 64 + wave * 16 + q * 4 + reg;
        if (gr >= n_rows) continue;
        float s = scale ? scale[gr] : 1.0f;
        #pragma unroll
        for (int ct = 0; ct < 8; ++ct) {
            out[(size_t)gr * out_stride + out_off + ct * 16 + m] =
                f2fp8(acc[ct][reg] * s);
        }
    }
}

// x_new[n] = relu( dinv[n] * (hs[n] + sum_{e in in(n)} hs[src_e]) + b )
// hs fp8 rows (128B); 8 lanes/node, uint4 = 16 ch/lane; A out bf16.
__global__ __launch_bounds__(256) void gcn_gather(
    const unsigned char* __restrict__ hs, const int* __restrict__ csr_src,
    const int* __restrict__ offs, const int* __restrict__ counts,
    const float* __restrict__ dinv, const float* __restrict__ bias,
    unsigned short* __restrict__ xout, int n)
{
    int node = blockIdx.x * 32 + (threadIdx.x >> 3);
    if (node >= n) return;
    int lane = threadIdx.x & 7;
    int c16 = lane * 16;
    int off = offs[node];
    int cnt = counts[node];

    float a[16] = {};
    de16add(*(const uint4*)(hs + (size_t)node * 128 + c16), a);  // self term

    int j = 0;
    for (; j + 4 <= cnt; j += 4) {
        int s0 = csr_src[off + j + 0];
        int s1 = csr_src[off + j + 1];
        int s2 = csr_src[off + j + 2];
        int s3 = csr_src[off + j + 3];
        uint4 h0 = *(const uint4*)(hs + (size_t)s0 * 128 + c16);
        uint4 h1 = *(const uint4*)(hs + (size_t)s1 * 128 + c16);
        uint4 h2 = *(const uint4*)(hs + (size_t)s2 * 128 + c16);
        uint4 h3 = *(const uint4*)(hs + (size_t)s3 * 128 + c16);
        de16add(h0, a); de16add(h1, a); de16add(h2, a); de16add(h3, a);
    }
    for (; j < cnt; ++j) {
        int s = csr_src[off + j];
        de16add(*(const uint4*)(hs + (size_t)s * 128 + c16), a);
    }

    float dn = dinv[node];
    float r[16];
    #pragma unroll
    for (int i = 0; i < 4; ++i) {
        float4 bb = *(const float4*)(bias + c16 + i * 4);
        r[i*4+0] = fmaxf(fmaf(a[i*4+0], dn, bb.x), 0.f);
        r[i*4+1] = fmaxf(fmaf(a[i*4+1], dn, bb.y), 0.f);
        r[i*4+2] = fmaxf(fmaf(a[i*4+2], dn, bb.z), 0.f);
        r[i*4+3] = fmaxf(fmaf(a[i*4+3], dn, bb.w), 0.f);
    }
    uint4 o0, o1;
    o0.x = pk2bf(r[0], r[1]);  o0.y = pk2bf(r[2], r[3]);
    o0.z = pk2bf(r[4], r[5]);  o0.w = pk2bf(r[6], r[7]);
    o1.x = pk2bf(r[8], r[9]);  o1.y = pk2bf(r[10], r[11]);
    o1.z = pk2bf(r[12], r[13]); o1.w = pk2bf(r[14], r[15]);
    *(uint4*)(xout + (size_t)node * 128 + c16) = o0;
    *(uint4*)(xout + (size_t)node * 128 + c16 + 8) = o1;
}

// acc += sum_e relu(u[src_e] + v[dst_e] + ea_e@We_ea + be) . Wg   (uv fp8)
#define EM_CHUNK 256
__global__ __launch_bounds__(256) void edge_mlp(
    const unsigned char* __restrict__ uv, const int* __restrict__ src,
    const int* __restrict__ dst, const float* __restrict__ ea,
    const float* __restrict__ We_e, const float* __restrict__ be,
    const float* __restrict__ Wg, float* __restrict__ acc, int E)
{
    const int tid  = threadIdx.x;
    const int lane = tid & 31;
    const int g    = tid >> 5;
    const int c4   = lane * 4;

    __shared__ float eas[EM_CHUNK * 7];
    __shared__ int   ss[EM_CHUNK];
    __shared__ int   ds[EM_CHUNK];
    __shared__ float red[256];

    float4 w[7];
    #pragma unroll
    for (int i = 0; i < 7; ++i)
        w[i] = *(const float4*)(We_e + i * 128 + c4);
    const float4 be4 = *(const float4*)(be + c4);
    const float4 wg4 = *(const float4*)(Wg + c4);

    float4 part = make_float4(0.f, 0.f, 0.f, 0.f);

    for (int base = blockIdx.x * EM_CHUNK; base < E; base += gridDim.x * EM_CHUNK) {
        const int nch = min(EM_CHUNK, E - base);
        for (int i = tid; i < nch * 7; i += 256)
            eas[i] = ea[(size_t)base * 7 + i];
        for (int i = tid; i < nch; i += 256) {
            ss[i] = src[base + i];
            ds[i] = dst[base + i];
        }
        __syncthreads();

        auto ev = [&](int j) {
            unsigned int us = *(const unsigned int*)(uv + (size_t)ss[j] * 256 + c4);
            unsigned int vs = *(const unsigned int*)(uv + (size_t)ds[j] * 256 + 128 + c4);
            float uf[4], vf[4];
            fp8x4(us, uf); fp8x4(vs, vf);
            const float* eav = &eas[j * 7];
            float4 val;
            val.x = uf[0] + vf[0] + be4.x;
            val.y = uf[1] + vf[1] + be4.y;
            val.z = uf[2] + vf[2] + be4.z;
            val.w = uf[3] + vf[3] + be4.w;
            #pragma unroll
            for (int i = 0; i < 7; ++i) {
                float e = eav[i];
                val.x = fmaf(e, w[i].x, val.x);
                val.y = fmaf(e, w[i].y, val.y);
                val.z = fmaf(e, w[i].z, val.z);
                val.w = fmaf(e, w[i].w, val.w);
            }
            part.x += fmaxf(val.x, 0.f);
            part.y += fmaxf(val.y, 0.f);
            part.z += fmaxf(val.z, 0.f);
            part.w += fmaxf(val.w, 0.f);
        };

        int j = g;
        for (; j + 32 <= nch; j += 32) {
            ev(j); ev(j + 8); ev(j + 16); ev(j + 24);
        }
        for (; j < nch; j += 8)
            ev(j);
        __syncthreads();
    }

    float p = part.x * wg4.x + part.y * wg4.y + part.z * wg4.z + part.w * wg4.w;
    red[tid] = p;
    __syncthreads();
    for (int s = 128; s > 0; s >>= 1) {
        if (tid < s) red[tid] += red[tid + s];
        __syncthreads();
    }
    if (tid == 0) atomicAdd(acc, red[0]);
}

// ---------------- CSR build ----------------
__global__ void count_edges(const int* __restrict__ dst, int* __restrict__ counts, int E)
{
    int e = blockIdx.x * 256 + threadIdx.x;
    if (e < E) atomicAdd(&counts[dst[e]], 1);
}

__global__ void compute_dinv(const int* __restrict__ counts, float* __restrict__ dinv, int n)
{
    int i = blockIdx.x * 256 + threadIdx.x;
    if (i < n) dinv[i] = rsqrtf((float)counts[i] + 1.0f);
}

__global__ void scan1(const int* __restrict__ counts, int* __restrict__ scanned,
                      int* __restrict__ btot, int n)
{
    __shared__ int sh[256];
    int i = blockIdx.x * 256 + threadIdx.x;
    int v = (i < n) ? counts[i] : 0;
    sh[threadIdx.x] = v;
    __syncthreads();
    for (int off = 1; off < 256; off <<= 1) {
        int t = (threadIdx.x >= off) ? sh[threadIdx.x - off] : 0;
        __syncthreads();
        sh[threadIdx.x] += t;
        __syncthreads();
    }
    if (i < n) scanned[i] = sh[threadIdx.x] - v;  // exclusive
    if (threadIdx.x == 255) btot[blockIdx.x] = sh[255];
}

__global__ void scan2(int* __restrict__ btot, int nb)
{
    __shared__ int sh[256];
    int v = (threadIdx.x < nb) ? btot[threadIdx.x] : 0;
    sh[threadIdx.x] = v;
    __syncthreads();
    for (int off = 1; off < 256; off <<= 1) {
        int t = (threadIdx.x >= off) ? sh[threadIdx.x - off] : 0;
        __syncthreads();
        sh[threadIdx.x] += t;
        __syncthreads();
    }
    if (threadIdx.x < nb) btot[threadIdx.x] = sh[threadIdx.x] - v;  // exclusive
}

__global__ void scan3(const int* __restrict__ scanned, const int* __restrict__ btot,
                      int* __restrict__ offs, int* __restrict__ cursor, int n)
{
    int i = blockIdx.x * 256 + threadIdx.x;
    if (i < n) {
        int o = scanned[i] + btot[blockIdx.x];
        offs[i] = o;
        cursor[i] = o;
    }
}

__global__ void fill_csr(const int* __restrict__ src, const int* __restrict__ dst,
                         int* __restrict__ cursor, int* __restrict__ csr_src, int E)
{
    int e = blockIdx.x * 256 + threadIdx.x;
    if (e < E) {
        int slot = atomicAdd(&cursor[dst[e]], 1);
        csr_src[slot] = src[e];
    }
}

__global__ void write_out(const float* __restrict__ acc, const float* __restrict__ bg,
                          float* __restrict__ out, float invE, int T)
{
    int t = threadIdx.x;
    if (t < T) out[t] = acc[t] * invE + bg[0];
}

// ---------------------------------------------------------------------------

extern "C" void kernel_launch(void* const* d_in, const int* in_sizes, int n_in,
                              void* d_out, int out_size, void* d_ws, size_t ws_size,
                              hipStream_t stream)
{
    const float* x   = (const float*)d_in[0];
    const int*  eidx = (const int*)d_in[1];
    const float* ea  = (const float*)d_in[2];
    const float* W1  = (const float*)d_in[3];
    const float* b1  = (const float*)d_in[4];
    const float* W2  = (const float*)d_in[5];
    const float* b2  = (const float*)d_in[6];
    const float* W3  = (const float*)d_in[7];
    const float* b3  = (const float*)d_in[8];
    const float* We  = (const float*)d_in[9];
    const float* be  = (const float*)d_in[10];
    const float* Wg  = (const float*)d_in[11];
    const float* bg  = (const float*)d_in[12];

    const int N = in_sizes[0] / 128;
    const int E = in_sizes[1] / 2;
    const int T = in_sizes[2] / (E * 7);
    const int* src = eidx;
    const int* dst = eidx + E;

    char* wsp = (char*)d_ws;
    auto alloc = [&](size_t bytes) -> char* {
        char* p = wsp;
        wsp += (bytes + 255) / 256 * 256;
        return p;
    };
    int*   counts  = (int*)alloc((size_t)N * 4);
    int*   offs    = (int*)alloc((size_t)N * 4);
    int*   cursor  = (int*)alloc((size_t)N * 4);
    int*   scanned = (int*)alloc((size_t)N * 4);
    int*   btot    = (int*)alloc(1024);
    int*   csr_src = (int*)alloc((size_t)E * 4);
    float* dinv    = (float*)alloc((size_t)N * 4);
    float* acc     = (float*)alloc(256);
    unsigned short* X0 = (unsigned short*)alloc((size_t)N * 128 * 2);  // x bf16
    unsigned short* A  = (unsigned short*)alloc((size_t)N * 128 * 2);  // evolving x bf16
    unsigned char*  B  = (unsigned char*)alloc((size_t)N * 256);       // hs/uv fp8
    unsigned short* W1b = (unsigned short*)alloc(128 * 128 * 2);
    unsigned short* W2b = (unsigned short*)alloc(128 * 128 * 2);
    unsigned short* W3b = (unsigned short*)alloc(128 * 128 * 2);
    unsigned short* Wuvb = (unsigned short*)alloc(256 * 128 * 2);      // We rows 0..255

    hipMemsetAsync(counts, 0, (size_t)N * 4, stream);
    hipMemsetAsync(acc, 0, (size_t)T * 4, stream);

    to_bf16<<<(N * 128 / 4 + 255) / 256, 256, 0, stream>>>(x, X0, N * 128 / 4);
    to_bf16<<<16, 256, 0, stream>>>(W1, W1b, 128 * 128 / 4);
    to_bf16<<<16, 256, 0, stream>>>(W2, W2b, 128 * 128 / 4);
    to_bf16<<<16, 256, 0, stream>>>(W3, W3b, 128 * 128 / 4);
    to_bf16<<<32, 256, 0, stream>>>(We, Wuvb, 256 * 128 / 4);

    count_edges<<<(E + 255) / 256, 256, 0, stream>>>(dst, counts, E);
    compute_dinv<<<(N + 255) / 256, 256, 0, stream>>>(counts, dinv, N);
    const int nb = (N + 255) / 256;
    scan1<<<nb, 256, 0, stream>>>(counts, scanned, btot, N);
    scan2<<<1, 256, 0, stream>>>(btot, nb);
    scan3<<<nb, 256, 0, stream>>>(scanned, btot, offs, cursor, N);
    fill_csr<<<(E + 255) / 256, 256, 0, stream>>>(src, dst, cursor, csr_src, E);

    const int mmb = (N + 63) / 64;
    const int ngb = (N + 31) / 32;
    const int emb = (E + EM_CHUNK - 1) / EM_CHUNK;

    for (int t = 0; t < T; ++t) {
        const unsigned short* xin = (t == 0) ? X0 : A;
        const unsigned short* Wc1 = (t == 0) ? W1b : W2b;  // ref rebinds W1=W2 after t=0
        mfma_matmul<<<mmb, 256, 0, stream>>>(xin, Wc1, B, dinv, N, 128, 0);
        gcn_gather<<<ngb, 256, 0, stream>>>(B, csr_src, offs, counts, dinv, b1, A, N);
        mfma_matmul<<<mmb, 256, 0, stream>>>(A, W2b, B, dinv, N, 128, 0);
        gcn_gather<<<ngb, 256, 0, stream>>>(B, csr_src, offs, counts, dinv, b2, A, N);
        mfma_matmul<<<mmb, 256, 0, stream>>>(A, W3b, B, dinv, N, 128, 0);
        gcn_gather<<<ngb, 256, 0, stream>>>(B, csr_src, offs, counts, dinv, b3, A, N);
        mfma_matmul<<<mmb, 256, 0, stream>>>(A, Wuvb, B, nullptr, N, 256, 0);
        mfma_matmul<<<mmb, 256, 0, stream>>>(A, Wuvb + 128 * 128, B, nullptr, N, 256, 128);
        edge_mlp<<<emb, 256, 0, stream>>>(B, src, dst, ea + (size_t)t * E * 7,
                                          We + 256 * 128, be, Wg, acc + t, E);
    }
    write_out<<<1, 64, 0, stream>>>(acc, bg, (float*)d_out, 1.0f / (float)E, T);
}

// Round 9
// 671.611 us; speedup vs baseline: 1.2612x; 1.0128x over previous
//
#include <hip/hip_runtime.h>
#include <hip/hip_bf16.h>

// ---------------------------------------------------------------------------
// GNN regression: per timestep t: 3x GCNConv(relu) then edge-MLP head.
//   edge head: relu(concat(x[s],x[d],ea)@We + be) . Wg
//            = relu(u[s] + v[d] + ea@We_ea + be) . Wg   with u=x@We[:128], v=x@We[128:256]
//   GCN agg:   CSR-by-dst gather; matmul epilogue pre-scales rows by dinv;
//              gather fuses self-loop+bias+relu.
// NOTE: reference rebinds W1=W2 after t=0 (`W1 = W2; W1 = W1`).
// R2: edge_mlp LDS-staged (375->124us). R3: NEUTRAL. R4: bf16 tables.
// R5: bf16 node tensors. R6: MFMA matmuls. R7: 847->771. R8: fp8 gathered
//     tables (edge 80->62us, FETCH halved); budget math exposed matmuls at
//     ~15-18us each: per-block LDS W-transpose (64 scattered ds_write_b16
//     per thread x 782 blocks) + 35KB LDS occupancy cap.
// R9: weights pre-transposed ONCE to global Wt[c][k] bf16; matmul v2 has no
//     LDS/no barriers, B-frags from L2-hot 64KB table; u/v merged into one
//     dispatch (gridDim.y=2). gcn_gather unrolled to 8 outstanding rows
//     (latency-bound: table 6.4MB L2/L3-resident, floor ~10us).
// ---------------------------------------------------------------------------

typedef __attribute__((ext_vector_type(8))) short bf16x8;
typedef __attribute__((ext_vector_type(4))) float f32x4;
typedef __attribute__((ext_vector_type(2))) float f32x2;

__device__ __forceinline__ unsigned short f2bf(float f) {
    union { float f; unsigned int u; } v; v.f = f;
    unsigned int r = v.u + 0x7fffu + ((v.u >> 16) & 1u);  // RNE
    return (unsigned short)(r >> 16);
}
__device__ __forceinline__ float bf2f(unsigned short h) {
    union { unsigned int u; float f; } v; v.u = ((unsigned int)h) << 16;
    return v.f;
}
__device__ __forceinline__ unsigned int pk2bf(float lo, float hi) {
    return (unsigned int)f2bf(lo) | ((unsigned int)f2bf(hi) << 16);
}
// fp8 e4m3 (OCP on gfx950) via HW converts
__device__ __forceinline__ unsigned char f2fp8(float f) {
    return (unsigned char)(__builtin_amdgcn_cvt_pk_fp8_f32(f, f, 0, false) & 0xff);
}
__device__ __forceinline__ void fp8x4(unsigned int u, float* o) {
    f32x2 lo = __builtin_amdgcn_cvt_pk_f32_fp8(u, false);
    f32x2 hi = __builtin_amdgcn_cvt_pk_f32_fp8(u, true);
    o[0] = lo[0]; o[1] = lo[1]; o[2] = hi[0]; o[3] = hi[1];
}
__device__ __forceinline__ void de16add(uint4 v, float* a) {
    float t[4];
    fp8x4(v.x, t); a[0]+=t[0]; a[1]+=t[1]; a[2]+=t[2]; a[3]+=t[3];
    fp8x4(v.y, t); a[4]+=t[0]; a[5]+=t[1]; a[6]+=t[2]; a[7]+=t[3];
    fp8x4(v.z, t); a[8]+=t[0]; a[9]+=t[1]; a[10]+=t[2]; a[11]+=t[3];
    fp8x4(v.w, t); a[12]+=t[0]; a[13]+=t[1]; a[14]+=t[2]; a[15]+=t[3];
}

__global__ void to_bf16(const float* __restrict__ in, unsigned short* __restrict__ out, int n4)
{
    int i = blockIdx.x * 256 + threadIdx.x;
    if (i < n4) {
        float4 v = ((const float4*)in)[i];
        ushort4 o;
        o.x = f2bf(v.x); o.y = f2bf(v.y); o.z = f2bf(v.z); o.w = f2bf(v.w);
        ((ushort4*)out)[i] = o;
    }
}

// Transpose 5x 128x128 fp32 weight blocks -> bf16 Wt[c*128+k], once per launch.
// blockIdx.y: 0=W1 1=W2 2=W3 3=We_u 4=We_v
__global__ void transpose_w(
    const float* __restrict__ W1, const float* __restrict__ W2,
    const float* __restrict__ W3, const float* __restrict__ We,
    unsigned short* __restrict__ T1, unsigned short* __restrict__ T2,
    unsigned short* __restrict__ T3, unsigned short* __restrict__ Tuv)
{
    const float* src; unsigned short* dst;
    switch (blockIdx.y) {
        case 0:  src = W1;             dst = T1;              break;
        case 1:  src = W2;             dst = T2;              break;
        case 2:  src = W3;             dst = T3;              break;
        case 3:  src = We;             dst = Tuv;             break;
        default: src = We + 128 * 128; dst = Tuv + 128 * 128; break;
    }
    for (int i = blockIdx.x * 256 + threadIdx.x; i < 128 * 128; i += 256 * gridDim.x) {
        int k = i >> 7, c = i & 127;
        dst[c * 128 + k] = f2bf(src[i]);
    }
}

// ---------------- MFMA matmul: out[r][c] = sum_k X[r][k]*W[k][c] ------------
// X bf16 [n,128]; Wt bf16 TRANSPOSED [c][k] (L2-hot 64KB); out fp8 rows.
// No LDS, no barriers. gridDim.y=2 handles u|v halves (Wt +=128*128, off+=128).
// Layouts (m89/m91): A[m=lane&15][k=quad*8+j]; C/D col=lane&15, row=quad*4+reg.
__global__ __launch_bounds__(256) void mfma_matmul(
    const unsigned short* __restrict__ X, const unsigned short* __restrict__ Wt,
    unsigned char* __restrict__ out, const float* __restrict__ scale,
    int n_rows, int out_stride, int out_off)
{
    if (blockIdx.y) { Wt += 128 * 128; out_off += 128; }

    const int wave = threadIdx.x >> 6;
    const int lane = threadIdx.x & 63;
    const int m = lane & 15;
    const int q = lane >> 4;
    const int r = blockIdx.x * 64 + wave * 16 + m;
    const bool rv = r < n_rows;

    f32x4 acc[8];
    #pragma unroll
    for (int i = 0; i < 8; ++i) acc[i] = (f32x4){0.f, 0.f, 0.f, 0.f};

    #pragma unroll
    for (int k0 = 0; k0 < 128; k0 += 32) {
        bf16x8 a = {};
        if (rv) a = *(const bf16x8*)(X + (size_t)r * 128 + k0 + q * 8);
        #pragma unroll
        for (int ct = 0; ct < 8; ++ct) {
            bf16x8 b = *(const bf16x8*)(Wt + (ct * 16 + m) * 128 + k0 + q * 8);
            acc[ct] = __builtin_amdgcn_mfma_f32_16x16x32_bf16(a, b, acc[ct], 0, 0, 0);
        }
    }

    #pragma unroll
    for (int reg = 0; reg < 4; ++reg) {
        int gr = blockIdx.x * 64 + wave * 16 + q * 4 + reg;
        if (gr >= n_rows) continue;
        float s = scale ? scale[gr] : 1.0f;
        #pragma unroll
        for (int ct = 0; ct < 8; ++ct) {
            out[(size_t)gr * out_stride + out_off + ct * 16 + m] =
                f2fp8(acc[ct][reg] * s);
        }
    }
}

// x_new[n] = relu( dinv[n] * (hs[n] + sum_{e in in(n)} hs[src_e]) + b )
// hs fp8 rows (128B); 8 lanes/node, uint4 = 16 ch/lane; unroll 8 for MLP.
__global__ __launch_bounds__(256) void gcn_gather(
    const unsigned char* __restrict__ hs, const int* __restrict__ csr_src,
    const int* __restrict__ offs, const int* __restrict__ counts,
    const float* __restrict__ dinv, const float* __restrict__ bias,
    unsigned short* __restrict__ xout, int n)
{
    int node = blockIdx.x * 32 + (threadIdx.x >> 3);
    if (node >= n) return;
    int lane = threadIdx.x & 7;
    int c16 = lane * 16;
    int off = offs[node];
    int cnt = counts[node];

    float a[16] = {};
    de16add(*(const uint4*)(hs + (size_t)node * 128 + c16), a);  // self term

    int j = 0;
    for (; j + 8 <= cnt; j += 8) {
        int s0 = csr_src[off + j + 0];
        int s1 = csr_src[off + j + 1];
        int s2 = csr_src[off + j + 2];
        int s3 = csr_src[off + j + 3];
        int s4 = csr_src[off + j + 4];
        int s5 = csr_src[off + j + 5];
        int s6 = csr_src[off + j + 6];
        int s7 = csr_src[off + j + 7];
        uint4 h0 = *(const uint4*)(hs + (size_t)s0 * 128 + c16);
        uint4 h1 = *(const uint4*)(hs + (size_t)s1 * 128 + c16);
        uint4 h2 = *(const uint4*)(hs + (size_t)s2 * 128 + c16);
        uint4 h3 = *(const uint4*)(hs + (size_t)s3 * 128 + c16);
        uint4 h4 = *(const uint4*)(hs + (size_t)s4 * 128 + c16);
        uint4 h5 = *(const uint4*)(hs + (size_t)s5 * 128 + c16);
        uint4 h6 = *(const uint4*)(hs + (size_t)s6 * 128 + c16);
        uint4 h7 = *(const uint4*)(hs + (size_t)s7 * 128 + c16);
        de16add(h0, a); de16add(h1, a); de16add(h2, a); de16add(h3, a);
        de16add(h4, a); de16add(h5, a); de16add(h6, a); de16add(h7, a);
    }
    for (; j + 4 <= cnt; j += 4) {
        int s0 = csr_src[off + j + 0];
        int s1 = csr_src[off + j + 1];
        int s2 = csr_src[off + j + 2];
        int s3 = csr_src[off + j + 3];
        uint4 h0 = *(const uint4*)(hs + (size_t)s0 * 128 + c16);
        uint4 h1 = *(const uint4*)(hs + (size_t)s1 * 128 + c16);
        uint4 h2 = *(const uint4*)(hs + (size_t)s2 * 128 + c16);
        uint4 h3 = *(const uint4*)(hs + (size_t)s3 * 128 + c16);
        de16add(h0, a); de16add(h1, a); de16add(h2, a); de16add(h3, a);
    }
    for (; j < cnt; ++j) {
        int s = csr_src[off + j];
        de16add(*(const uint4*)(hs + (size_t)s * 128 + c16), a);
    }

    float dn = dinv[node];
    float r[16];
    #pragma unroll
    for (int i = 0; i < 4; ++i) {
        float4 bb = *(const float4*)(bias + c16 + i * 4);
        r[i*4+0] = fmaxf(fmaf(a[i*4+0], dn, bb.x), 0.f);
        r[i*4+1] = fmaxf(fmaf(a[i*4+1], dn, bb.y), 0.f);
        r[i*4+2] = fmaxf(fmaf(a[i*4+2], dn, bb.z), 0.f);
        r[i*4+3] = fmaxf(fmaf(a[i*4+3], dn, bb.w), 0.f);
    }
    uint4 o0, o1;
    o0.x = pk2bf(r[0], r[1]);  o0.y = pk2bf(r[2], r[3]);
    o0.z = pk2bf(r[4], r[5]);  o0.w = pk2bf(r[6], r[7]);
    o1.x = pk2bf(r[8], r[9]);  o1.y = pk2bf(r[10], r[11]);
    o1.z = pk2bf(r[12], r[13]); o1.w = pk2bf(r[14], r[15]);
    *(uint4*)(xout + (size_t)node * 128 + c16) = o0;
    *(uint4*)(xout + (size_t)node * 128 + c16 + 8) = o1;
}

// acc += sum_e relu(u[src_e] + v[dst_e] + ea_e@We_ea + be) . Wg   (uv fp8)
#define EM_CHUNK 256
__global__ __launch_bounds__(256) void edge_mlp(
    const unsigned char* __restrict__ uv, const int* __restrict__ src,
    const int* __restrict__ dst, const float* __restrict__ ea,
    const float* __restrict__ We_e, const float* __restrict__ be,
    const float* __restrict__ Wg, float* __restrict__ acc, int E)
{
    const int tid  = threadIdx.x;
    const int lane = tid & 31;
    const int g    = tid >> 5;
    const int c4   = lane * 4;

    __shared__ float eas[EM_CHUNK * 7];
    __shared__ int   ss[EM_CHUNK];
    __shared__ int   ds[EM_CHUNK];
    __shared__ float red[256];

    float4 w[7];
    #pragma unroll
    for (int i = 0; i < 7; ++i)
        w[i] = *(const float4*)(We_e + i * 128 + c4);
    const float4 be4 = *(const float4*)(be + c4);
    const float4 wg4 = *(const float4*)(Wg + c4);

    float4 part = make_float4(0.f, 0.f, 0.f, 0.f);

    for (int base = blockIdx.x * EM_CHUNK; base < E; base += gridDim.x * EM_CHUNK) {
        const int nch = min(EM_CHUNK, E - base);
        for (int i = tid; i < nch * 7; i += 256)
            eas[i] = ea[(size_t)base * 7 + i];
        for (int i = tid; i < nch; i += 256) {
            ss[i] = src[base + i];
            ds[i] = dst[base + i];
        }
        __syncthreads();

        auto ev = [&](int j) {
            unsigned int us = *(const unsigned int*)(uv + (size_t)ss[j] * 256 + c4);
            unsigned int vs = *(const unsigned int*)(uv + (size_t)ds[j] * 256 + 128 + c4);
            float uf[4], vf[4];
            fp8x4(us, uf); fp8x4(vs, vf);
            const float* eav = &eas[j * 7];
            float4 val;
            val.x = uf[0] + vf[0] + be4.x;
            val.y = uf[1] + vf[1] + be4.y;
            val.z = uf[2] + vf[2] + be4.z;
            val.w = uf[3] + vf[3] + be4.w;
            #pragma unroll
            for (int i = 0; i < 7; ++i) {
                float e = eav[i];
                val.x = fmaf(e, w[i].x, val.x);
                val.y = fmaf(e, w[i].y, val.y);
                val.z = fmaf(e, w[i].z, val.z);
                val.w = fmaf(e, w[i].w, val.w);
            }
            part.x += fmaxf(val.x, 0.f);
            part.y += fmaxf(val.y, 0.f);
            part.z += fmaxf(val.z, 0.f);
            part.w += fmaxf(val.w, 0.f);
        };

        int j = g;
        for (; j + 32 <= nch; j += 32) {
            ev(j); ev(j + 8); ev(j + 16); ev(j + 24);
        }
        for (; j < nch; j += 8)
            ev(j);
        __syncthreads();
    }

    float p = part.x * wg4.x + part.y * wg4.y + part.z * wg4.z + part.w * wg4.w;
    red[tid] = p;
    __syncthreads();
    for (int s = 128; s > 0; s >>= 1) {
        if (tid < s) red[tid] += red[tid + s];
        __syncthreads();
    }
    if (tid == 0) atomicAdd(acc, red[0]);
}

// ---------------- CSR build ----------------
__global__ void count_edges(const int* __restrict__ dst, int* __restrict__ counts, int E)
{
    int e = blockIdx.x * 256 + threadIdx.x;
    if (e < E) atomicAdd(&counts[dst[e]], 1);
}

__global__ void compute_dinv(const int* __restrict__ counts, float* __restrict__ dinv, int n)
{
    int i = blockIdx.x * 256 + threadIdx.x;
    if (i < n) dinv[i] = rsqrtf((float)counts[i] + 1.0f);
}

__global__ void scan1(const int* __restrict__ counts, int* __restrict__ scanned,
                      int* __restrict__ btot, int n)
{
    __shared__ int sh[256];
    int i = blockIdx.x * 256 + threadIdx.x;
    int v = (i < n) ? counts[i] : 0;
    sh[threadIdx.x] = v;
    __syncthreads();
    for (int off = 1; off < 256; off <<= 1) {
        int t = (threadIdx.x >= off) ? sh[threadIdx.x - off] : 0;
        __syncthreads();
        sh[threadIdx.x] += t;
        __syncthreads();
    }
    if (i < n) scanned[i] = sh[threadIdx.x] - v;  // exclusive
    if (threadIdx.x == 255) btot[blockIdx.x] = sh[255];
}

__global__ void scan2(int* __restrict__ btot, int nb)
{
    __shared__ int sh[256];
    int v = (threadIdx.x < nb) ? btot[threadIdx.x] : 0;
    sh[threadIdx.x] = v;
    __syncthreads();
    for (int off = 1; off < 256; off <<= 1) {
        int t = (threadIdx.x >= off) ? sh[threadIdx.x - off] : 0;
        __syncthreads();
        sh[threadIdx.x] += t;
        __syncthreads();
    }
    if (threadIdx.x < nb) btot[threadIdx.x] = sh[threadIdx.x] - v;  // exclusive
}

__global__ void scan3(const int* __restrict__ scanned, const int* __restrict__ btot,
                      int* __restrict__ offs, int* __restrict__ cursor, int n)
{
    int i = blockIdx.x * 256 + threadIdx.x;
    if (i < n) {
        int o = scanned[i] + btot[blockIdx.x];
        offs[i] = o;
        cursor[i] = o;
    }
}

__global__ void fill_csr(const int* __restrict__ src, const int* __restrict__ dst,
                         int* __restrict__ cursor, int* __restrict__ csr_src, int E)
{
    int e = blockIdx.x * 256 + threadIdx.x;
    if (e < E) {
        int slot = atomicAdd(&cursor[dst[e]], 1);
        csr_src[slot] = src[e];
    }
}

__global__ void write_out(const float* __restrict__ acc, const float* __restrict__ bg,
                          float* __restrict__ out, float invE, int T)
{
    int t = threadIdx.x;
    if (t < T) out[t] = acc[t] * invE + bg[0];
}

// ---------------------------------------------------------------------------

extern "C" void kernel_launch(void* const* d_in, const int* in_sizes, int n_in,
                              void* d_out, int out_size, void* d_ws, size_t ws_size,
                              hipStream_t stream)
{
    const float* x   = (const float*)d_in[0];
    const int*  eidx = (const int*)d_in[1];
    const float* ea  = (const float*)d_in[2];
    const float* W1  = (const float*)d_in[3];
    const float* b1  = (const float*)d_in[4];
    const float* W2  = (const float*)d_in[5];
    const float* b2  = (const float*)d_in[6];
    const float* W3  = (const float*)d_in[7];
    const float* b3  = (const float*)d_in[8];
    const float* We  = (const float*)d_in[9];
    const float* be  = (const float*)d_in[10];
    const float* Wg  = (const float*)d_in[11];
    const float* bg  = (const float*)d_in[12];

    const int N = in_sizes[0] / 128;
    const int E = in_sizes[1] / 2;
    const int T = in_sizes[2] / (E * 7);
    const int* src = eidx;
    const int* dst = eidx + E;

    char* wsp = (char*)d_ws;
    auto alloc = [&](size_t bytes) -> char* {
        char* p = wsp;
        wsp += (bytes + 255) / 256 * 256;
        return p;
    };
    int*   counts  = (int*)alloc((size_t)N * 4);
    int*   offs    = (int*)alloc((size_t)N * 4);
    int*   cursor  = (int*)alloc((size_t)N * 4);
    int*   scanned = (int*)alloc((size_t)N * 4);
    int*   btot    = (int*)alloc(1024);
    int*   csr_src = (int*)alloc((size_t)E * 4);
    float* dinv    = (float*)alloc((size_t)N * 4);
    float* acc     = (float*)alloc(256);
    unsigned short* X0 = (unsigned short*)alloc((size_t)N * 128 * 2);  // x bf16
    unsigned short* A  = (unsigned short*)alloc((size_t)N * 128 * 2);  // evolving x bf16
    unsigned char*  B  = (unsigned char*)alloc((size_t)N * 256);       // hs/uv fp8
    unsigned short* T1 = (unsigned short*)alloc(128 * 128 * 2);        // W^T bf16
    unsigned short* T2 = (unsigned short*)alloc(128 * 128 * 2);
    unsigned short* T3 = (unsigned short*)alloc(128 * 128 * 2);
    unsigned short* Tuv = (unsigned short*)alloc(256 * 128 * 2);

    hipMemsetAsync(counts, 0, (size_t)N * 4, stream);
    hipMemsetAsync(acc, 0, (size_t)T * 4, stream);

    to_bf16<<<(N * 128 / 4 + 255) / 256, 256, 0, stream>>>(x, X0, N * 128 / 4);
    transpose_w<<<dim3(4, 5), 256, 0, stream>>>(W1, W2, W3, We, T1, T2, T3, Tuv);

    count_edges<<<(E + 255) / 256, 256, 0, stream>>>(dst, counts, E);
    compute_dinv<<<(N + 255) / 256, 256, 0, stream>>>(counts, dinv, N);
    const int nb = (N + 255) / 256;
    scan1<<<nb, 256, 0, stream>>>(counts, scanned, btot, N);
    scan2<<<1, 256, 0, stream>>>(btot, nb);
    scan3<<<nb, 256, 0, stream>>>(scanned, btot, offs, cursor, N);
    fill_csr<<<(E + 255) / 256, 256, 0, stream>>>(src, dst, cursor, csr_src, E);

    const int mmb = (N + 63) / 64;
    const int ngb = (N + 31) / 32;
    const int emb = (E + EM_CHUNK - 1) / EM_CHUNK;

    for (int t = 0; t < T; ++t) {
        const unsigned short* xin = (t == 0) ? X0 : A;
        const unsigned short* Tc1 = (t == 0) ? T1 : T2;  // ref rebinds W1=W2 after t=0
        mfma_matmul<<<dim3(mmb, 1), 256, 0, stream>>>(xin, Tc1, B, dinv, N, 128, 0);
        gcn_gather<<<ngb, 256, 0, stream>>>(B, csr_src, offs, counts, dinv, b1, A, N);
        mfma_matmul<<<dim3(mmb, 1), 256, 0, stream>>>(A, T2, B, dinv, N, 128, 0);
        gcn_gather<<<ngb, 256, 0, stream>>>(B, csr_src, offs, counts, dinv, b2, A, N);
        mfma_matmul<<<dim3(mmb, 1), 256, 0, stream>>>(A, T3, B, dinv, N, 128, 0);
        gcn_gather<<<ngb, 256, 0, stream>>>(B, csr_src, offs, counts, dinv, b3, A, N);
        mfma_matmul<<<dim3(mmb, 2), 256, 0, stream>>>(A, Tuv, B, nullptr, N, 256, 0);
        edge_mlp<<<emb, 256, 0, stream>>>(B, src, dst, ea + (size_t)t * E * 7,
                                          We + 256 * 128, be, Wg, acc + t, E);
    }
    write_out<<<1, 64, 0, stream>>>(acc, bg, (float*)d_out, 1.0f / (float)E, T);
}

// Round 10
// 613.523 us; speedup vs baseline: 1.3806x; 1.0947x over previous
//
#include <hip/hip_runtime.h>
#include <hip/hip_bf16.h>

// ---------------------------------------------------------------------------
// GNN regression: per timestep t: 3x GCNConv(relu) then edge-MLP head.
//   edge head: relu(concat(x[s],x[d],ea)@We + be) . Wg
//            = relu(u[s] + v[d] + ea@We_ea + be) . Wg,  u=x@We[:128], v=x@We[128:256]
//   GCN agg via CSR-by-dst gather; agg(xW)=agg(x)W; row scale dinv folded in.
// NOTE: reference rebinds W1=W2 after t=0 (`W1 = W2; W1 = W1`).
// R2..R8: edge_mlp LDS-staged (375->124->84->62us via bf16/fp8 tables);
//   MFMA matmuls; fp8 gathered tables. R9 (LDS-transpose removal, unroll-8
//   gather): NEUTRAL -> middle-time attribution was wrong.
// R10: FUSE gather_k + matmul_{k+1}: per block, gather 64 nodes -> relu rows
//   (bf16) in LDS -> MFMA vs L2-hot Wt -> fp8 out. Eliminates the A tensor
//   (~150MB traffic), cuts loop dispatches 16->9, overlaps gather latency of
//   some blocks with MFMA of others. Timestep boundary: one fused kernel
//   computes [We_u|We_v|W2] (384 cols) -> uv AND next hs1 (W1:=W2 rebind),
//   x3 never materialized. Double-buffered hs (Bh0/Bh1) avoids WAR.
// ---------------------------------------------------------------------------

typedef __attribute__((ext_vector_type(8))) short bf16x8;
typedef __attribute__((ext_vector_type(4))) float f32x4;
typedef __attribute__((ext_vector_type(2))) float f32x2;

__device__ __forceinline__ unsigned short f2bf(float f) {
    union { float f; unsigned int u; } v; v.f = f;
    unsigned int r = v.u + 0x7fffu + ((v.u >> 16) & 1u);  // RNE
    return (unsigned short)(r >> 16);
}
__device__ __forceinline__ unsigned int pk2bf(float lo, float hi) {
    return (unsigned int)f2bf(lo) | ((unsigned int)f2bf(hi) << 16);
}
// fp8 e4m3 (OCP on gfx950) via HW converts
__device__ __forceinline__ unsigned char f2fp8(float f) {
    return (unsigned char)(__builtin_amdgcn_cvt_pk_fp8_f32(f, f, 0, false) & 0xff);
}
__device__ __forceinline__ void fp8x4(unsigned int u, float* o) {
    f32x2 lo = __builtin_amdgcn_cvt_pk_f32_fp8(u, false);
    f32x2 hi = __builtin_amdgcn_cvt_pk_f32_fp8(u, true);
    o[0] = lo[0]; o[1] = lo[1]; o[2] = hi[0]; o[3] = hi[1];
}
__device__ __forceinline__ void de16add(uint4 v, float* a) {
    float t[4];
    fp8x4(v.x, t); a[0]+=t[0]; a[1]+=t[1]; a[2]+=t[2]; a[3]+=t[3];
    fp8x4(v.y, t); a[4]+=t[0]; a[5]+=t[1]; a[6]+=t[2]; a[7]+=t[3];
    fp8x4(v.z, t); a[8]+=t[0]; a[9]+=t[1]; a[10]+=t[2]; a[11]+=t[3];
    fp8x4(v.w, t); a[12]+=t[0]; a[13]+=t[1]; a[14]+=t[2]; a[15]+=t[3];
}

__global__ void to_bf16(const float* __restrict__ in, unsigned short* __restrict__ out, int n4)
{
    int i = blockIdx.x * 256 + threadIdx.x;
    if (i < n4) {
        float4 v = ((const float4*)in)[i];
        ushort4 o;
        o.x = f2bf(v.x); o.y = f2bf(v.y); o.z = f2bf(v.z); o.w = f2bf(v.w);
        ((ushort4*)out)[i] = o;
    }
}

// Transpose weight blocks -> bf16 Wt[c*128+k], once per launch.
// y: 0:W1->T1  1:W2->T2  2:W3->T3  3:We_u->Tuv[0]  4:We_v->Tuv[128^2]
//    5:W2->Tuv[256*128]  (boundary fused kernel's extra cols = next-t conv1)
__global__ void transpose_w(
    const float* __restrict__ W1, const float* __restrict__ W2,
    const float* __restrict__ W3, const float* __restrict__ We,
    unsigned short* __restrict__ T1, unsigned short* __restrict__ T2,
    unsigned short* __restrict__ T3, unsigned short* __restrict__ Tuv)
{
    const float* src; unsigned short* dst;
    switch (blockIdx.y) {
        case 0:  src = W1;             dst = T1;               break;
        case 1:  src = W2;             dst = T2;               break;
        case 2:  src = W3;             dst = T3;               break;
        case 3:  src = We;             dst = Tuv;              break;
        case 4:  src = We + 128 * 128; dst = Tuv + 128 * 128;  break;
        default: src = W2;             dst = Tuv + 256 * 128;  break;
    }
    for (int i = blockIdx.x * 256 + threadIdx.x; i < 128 * 128; i += 256 * gridDim.x) {
        int k = i >> 7, c = i & 127;
        dst[c * 128 + k] = f2bf(src[i]);
    }
}

// ---------------- standalone MFMA matmul (t=0 conv1 only) -------------------
// out[r][c] = sum_k X[r][k]*W[k][c]; X bf16, Wt bf16 [c][k]; out fp8, scaled.
// Layouts (m89/m91): A[m=lane&15][k=quad*8+j]; C/D col=lane&15, row=quad*4+reg.
__global__ __launch_bounds__(256) void mfma_matmul(
    const unsigned short* __restrict__ X, const unsigned short* __restrict__ Wt,
    unsigned char* __restrict__ out, const float* __restrict__ scale, int n_rows)
{
    const int wave = threadIdx.x >> 6;
    const int lane = threadIdx.x & 63;
    const int m = lane & 15;
    const int q = lane >> 4;
    const int r = blockIdx.x * 64 + wave * 16 + m;
    const bool rv = r < n_rows;

    f32x4 acc[8];
    #pragma unroll
    for (int i = 0; i < 8; ++i) acc[i] = (f32x4){0.f, 0.f, 0.f, 0.f};

    #pragma unroll
    for (int k0 = 0; k0 < 128; k0 += 32) {
        bf16x8 a = {};
        if (rv) a = *(const bf16x8*)(X + (size_t)r * 128 + k0 + q * 8);
        #pragma unroll
        for (int ct = 0; ct < 8; ++ct) {
            bf16x8 b = *(const bf16x8*)(Wt + (ct * 16 + m) * 128 + k0 + q * 8);
            acc[ct] = __builtin_amdgcn_mfma_f32_16x16x32_bf16(a, b, acc[ct], 0, 0, 0);
        }
    }

    #pragma unroll
    for (int reg = 0; reg < 4; ++reg) {
        int gr = blockIdx.x * 64 + wave * 16 + q * 4 + reg;
        if (gr >= n_rows) continue;
        float s = scale[gr];
        #pragma unroll
        for (int ct = 0; ct < 8; ++ct)
            out[(size_t)gr * 128 + ct * 16 + m] = f2fp8(acc[ct][reg] * s);
    }
}

// ---------------- FUSED gather + matmul -------------------------------------
// Per block: 64 nodes. Phase A: gather hs_in rows (fp8) via CSR, normalize
// (dinv,bias,relu) -> x rows bf16 in LDS. Phase B: MFMA x @ Wt (ncols wide).
// Col c < uvcols -> buv[node*256+c] (unscaled); else -> bh[node*128+c-uvcols]
// scaled by dinv[node] (= next hs pre-scaled).
#define FPAD 136
__global__ __launch_bounds__(256) void fused_gm(
    const unsigned char* __restrict__ hs_in, const int* __restrict__ csr_src,
    const int* __restrict__ offs, const int* __restrict__ counts,
    const float* __restrict__ dinv, const float* __restrict__ bias,
    const unsigned short* __restrict__ Wt, int ncols, int uvcols,
    unsigned char* __restrict__ buv, unsigned char* __restrict__ bh, int n)
{
    __shared__ unsigned short xs[64 * FPAD];
    const int tid = threadIdx.x;

    // ---- Phase A: gather 64 nodes (two halves of 32; 8 lanes/node x 16ch) --
    #pragma unroll
    for (int half = 0; half < 2; ++half) {
        int row  = half * 32 + (tid >> 3);
        int node = blockIdx.x * 64 + row;
        if (node < n) {
            int c16 = (tid & 7) * 16;
            int off = offs[node];
            int cnt = counts[node];

            float a[16] = {};
            de16add(*(const uint4*)(hs_in + (size_t)node * 128 + c16), a);  // self
            int j = 0;
            for (; j + 4 <= cnt; j += 4) {
                int s0 = csr_src[off + j + 0];
                int s1 = csr_src[off + j + 1];
                int s2 = csr_src[off + j + 2];
                int s3 = csr_src[off + j + 3];
                uint4 h0 = *(const uint4*)(hs_in + (size_t)s0 * 128 + c16);
                uint4 h1 = *(const uint4*)(hs_in + (size_t)s1 * 128 + c16);
                uint4 h2 = *(const uint4*)(hs_in + (size_t)s2 * 128 + c16);
                uint4 h3 = *(const uint4*)(hs_in + (size_t)s3 * 128 + c16);
                de16add(h0, a); de16add(h1, a); de16add(h2, a); de16add(h3, a);
            }
            for (; j < cnt; ++j) {
                int s = csr_src[off + j];
                de16add(*(const uint4*)(hs_in + (size_t)s * 128 + c16), a);
            }

            float dn = dinv[node];
            #pragma unroll
            for (int i = 0; i < 4; ++i) {
                float4 bb = *(const float4*)(bias + c16 + i * 4);
                float r0 = fmaxf(fmaf(a[i*4+0], dn, bb.x), 0.f);
                float r1 = fmaxf(fmaf(a[i*4+1], dn, bb.y), 0.f);
                float r2 = fmaxf(fmaf(a[i*4+2], dn, bb.z), 0.f);
                float r3 = fmaxf(fmaf(a[i*4+3], dn, bb.w), 0.f);
                *(unsigned int*)&xs[row * FPAD + c16 + i*4 + 0] = pk2bf(r0, r1);
                *(unsigned int*)&xs[row * FPAD + c16 + i*4 + 2] = pk2bf(r2, r3);
            }
        }
    }
    __syncthreads();

    // ---- Phase B: MFMA x(LDS) @ Wt -> fp8 outputs --------------------------
    const int wave = tid >> 6;
    const int lane = tid & 63;
    const int m = lane & 15;
    const int q = lane >> 4;
    const int nct = ncols >> 4;

    for (int ct = 0; ct < nct; ++ct) {
        f32x4 acc = (f32x4){0.f, 0.f, 0.f, 0.f};
        #pragma unroll
        for (int k0 = 0; k0 < 128; k0 += 32) {
            bf16x8 a = *(const bf16x8*)&xs[(wave * 16 + m) * FPAD + k0 + q * 8];
            bf16x8 b = *(const bf16x8*)(Wt + (size_t)(ct * 16 + m) * 128 + k0 + q * 8);
            acc = __builtin_amdgcn_mfma_f32_16x16x32_bf16(a, b, acc, 0, 0, 0);
        }
        int col = ct * 16 + m;
        #pragma unroll
        for (int reg = 0; reg < 4; ++reg) {
            int node = blockIdx.x * 64 + wave * 16 + q * 4 + reg;
            if (node >= n) continue;
            if (col < uvcols)
                buv[(size_t)node * 256 + col] = f2fp8(acc[reg]);
            else
                bh[(size_t)node * 128 + col - uvcols] = f2fp8(acc[reg] * dinv[node]);
        }
    }
}

// acc += sum_e relu(u[src_e] + v[dst_e] + ea_e@We_ea + be) . Wg   (uv fp8)
#define EM_CHUNK 256
__global__ __launch_bounds__(256) void edge_mlp(
    const unsigned char* __restrict__ uv, const int* __restrict__ src,
    const int* __restrict__ dst, const float* __restrict__ ea,
    const float* __restrict__ We_e, const float* __restrict__ be,
    const float* __restrict__ Wg, float* __restrict__ acc, int E)
{
    const int tid  = threadIdx.x;
    const int lane = tid & 31;
    const int g    = tid >> 5;
    const int c4   = lane * 4;

    __shared__ float eas[EM_CHUNK * 7];
    __shared__ int   ss[EM_CHUNK];
    __shared__ int   ds[EM_CHUNK];
    __shared__ float red[256];

    float4 w[7];
    #pragma unroll
    for (int i = 0; i < 7; ++i)
        w[i] = *(const float4*)(We_e + i * 128 + c4);
    const float4 be4 = *(const float4*)(be + c4);
    const float4 wg4 = *(const float4*)(Wg + c4);

    float4 part = make_float4(0.f, 0.f, 0.f, 0.f);

    for (int base = blockIdx.x * EM_CHUNK; base < E; base += gridDim.x * EM_CHUNK) {
        const int nch = min(EM_CHUNK, E - base);
        for (int i = tid; i < nch * 7; i += 256)
            eas[i] = ea[(size_t)base * 7 + i];
        for (int i = tid; i < nch; i += 256) {
            ss[i] = src[base + i];
            ds[i] = dst[base + i];
        }
        __syncthreads();

        auto ev = [&](int j) {
            unsigned int us = *(const unsigned int*)(uv + (size_t)ss[j] * 256 + c4);
            unsigned int vs = *(const unsigned int*)(uv + (size_t)ds[j] * 256 + 128 + c4);
            float uf[4], vf[4];
            fp8x4(us, uf); fp8x4(vs, vf);
            const float* eav = &eas[j * 7];
            float4 val;
            val.x = uf[0] + vf[0] + be4.x;
            val.y = uf[1] + vf[1] + be4.y;
            val.z = uf[2] + vf[2] + be4.z;
            val.w = uf[3] + vf[3] + be4.w;
            #pragma unroll
            for (int i = 0; i < 7; ++i) {
                float e = eav[i];
                val.x = fmaf(e, w[i].x, val.x);
                val.y = fmaf(e, w[i].y, val.y);
                val.z = fmaf(e, w[i].z, val.z);
                val.w = fmaf(e, w[i].w, val.w);
            }
            part.x += fmaxf(val.x, 0.f);
            part.y += fmaxf(val.y, 0.f);
            part.z += fmaxf(val.z, 0.f);
            part.w += fmaxf(val.w, 0.f);
        };

        int j = g;
        for (; j + 32 <= nch; j += 32) {
            ev(j); ev(j + 8); ev(j + 16); ev(j + 24);
        }
        for (; j < nch; j += 8)
            ev(j);
        __syncthreads();
    }

    float p = part.x * wg4.x + part.y * wg4.y + part.z * wg4.z + part.w * wg4.w;
    red[tid] = p;
    __syncthreads();
    for (int s = 128; s > 0; s >>= 1) {
        if (tid < s) red[tid] += red[tid + s];
        __syncthreads();
    }
    if (tid == 0) atomicAdd(acc, red[0]);
}

// ---------------- CSR build ----------------
__global__ void count_edges(const int* __restrict__ dst, int* __restrict__ counts, int E)
{
    int e = blockIdx.x * 256 + threadIdx.x;
    if (e < E) atomicAdd(&counts[dst[e]], 1);
}

__global__ void compute_dinv(const int* __restrict__ counts, float* __restrict__ dinv, int n)
{
    int i = blockIdx.x * 256 + threadIdx.x;
    if (i < n) dinv[i] = rsqrtf((float)counts[i] + 1.0f);
}

__global__ void scan1(const int* __restrict__ counts, int* __restrict__ scanned,
                      int* __restrict__ btot, int n)
{
    __shared__ int sh[256];
    int i = blockIdx.x * 256 + threadIdx.x;
    int v = (i < n) ? counts[i] : 0;
    sh[threadIdx.x] = v;
    __syncthreads();
    for (int off = 1; off < 256; off <<= 1) {
        int t = (threadIdx.x >= off) ? sh[threadIdx.x - off] : 0;
        __syncthreads();
        sh[threadIdx.x] += t;
        __syncthreads();
    }
    if (i < n) scanned[i] = sh[threadIdx.x] - v;  // exclusive
    if (threadIdx.x == 255) btot[blockIdx.x] = sh[255];
}

__global__ void scan2(int* __restrict__ btot, int nb)
{
    __shared__ int sh[256];
    int v = (threadIdx.x < nb) ? btot[threadIdx.x] : 0;
    sh[threadIdx.x] = v;
    __syncthreads();
    for (int off = 1; off < 256; off <<= 1) {
        int t = (threadIdx.x >= off) ? sh[threadIdx.x - off] : 0;
        __syncthreads();
        sh[threadIdx.x] += t;
        __syncthreads();
    }
    if (threadIdx.x < nb) btot[threadIdx.x] = sh[threadIdx.x] - v;  // exclusive
}

__global__ void scan3(const int* __restrict__ scanned, const int* __restrict__ btot,
                      int* __restrict__ offs, int* __restrict__ cursor, int n)
{
    int i = blockIdx.x * 256 + threadIdx.x;
    if (i < n) {
        int o = scanned[i] + btot[blockIdx.x];
        offs[i] = o;
        cursor[i] = o;
    }
}

__global__ void fill_csr(const int* __restrict__ src, const int* __restrict__ dst,
                         int* __restrict__ cursor, int* __restrict__ csr_src, int E)
{
    int e = blockIdx.x * 256 + threadIdx.x;
    if (e < E) {
        int slot = atomicAdd(&cursor[dst[e]], 1);
        csr_src[slot] = src[e];
    }
}

__global__ void write_out(const float* __restrict__ acc, const float* __restrict__ bg,
                          float* __restrict__ out, float invE, int T)
{
    int t = threadIdx.x;
    if (t < T) out[t] = acc[t] * invE + bg[0];
}

// ---------------------------------------------------------------------------

extern "C" void kernel_launch(void* const* d_in, const int* in_sizes, int n_in,
                              void* d_out, int out_size, void* d_ws, size_t ws_size,
                              hipStream_t stream)
{
    const float* x   = (const float*)d_in[0];
    const int*  eidx = (const int*)d_in[1];
    const float* ea  = (const float*)d_in[2];
    const float* W1  = (const float*)d_in[3];
    const float* b1  = (const float*)d_in[4];
    const float* W2  = (const float*)d_in[5];
    const float* b2  = (const float*)d_in[6];
    const float* W3  = (const float*)d_in[7];
    const float* b3  = (const float*)d_in[8];
    const float* We  = (const float*)d_in[9];
    const float* be  = (const float*)d_in[10];
    const float* Wg  = (const float*)d_in[11];
    const float* bg  = (const float*)d_in[12];

    const int N = in_sizes[0] / 128;
    const int E = in_sizes[1] / 2;
    const int T = in_sizes[2] / (E * 7);
    const int* src = eidx;
    const int* dst = eidx + E;

    char* wsp = (char*)d_ws;
    auto alloc = [&](size_t bytes) -> char* {
        char* p = wsp;
        wsp += (bytes + 255) / 256 * 256;
        return p;
    };
    int*   counts  = (int*)alloc((size_t)N * 4);
    int*   offs    = (int*)alloc((size_t)N * 4);
    int*   cursor  = (int*)alloc((size_t)N * 4);
    int*   scanned = (int*)alloc((size_t)N * 4);
    int*   btot    = (int*)alloc(1024);
    int*   csr_src = (int*)alloc((size_t)E * 4);
    float* dinv    = (float*)alloc((size_t)N * 4);
    float* acc     = (float*)alloc(256);
    unsigned short* X0  = (unsigned short*)alloc((size_t)N * 128 * 2);  // x bf16
    unsigned char*  Bh0 = (unsigned char*)alloc((size_t)N * 128);       // hs fp8 (dbuf)
    unsigned char*  Bh1 = (unsigned char*)alloc((size_t)N * 128);
    unsigned char*  Buv = (unsigned char*)alloc((size_t)N * 256);       // uv fp8
    unsigned short* T1  = (unsigned short*)alloc(128 * 128 * 2);        // W^T bf16
    unsigned short* T2  = (unsigned short*)alloc(128 * 128 * 2);
    unsigned short* T3  = (unsigned short*)alloc(128 * 128 * 2);
    unsigned short* Tuv = (unsigned short*)alloc(384 * 128 * 2);        // [We_u|We_v|W2]^T

    hipMemsetAsync(counts, 0, (size_t)N * 4, stream);
    hipMemsetAsync(acc, 0, (size_t)T * 4, stream);

    to_bf16<<<(N * 128 / 4 + 255) / 256, 256, 0, stream>>>(x, X0, N * 128 / 4);
    transpose_w<<<dim3(8, 6), 256, 0, stream>>>(W1, W2, W3, We, T1, T2, T3, Tuv);

    count_edges<<<(E + 255) / 256, 256, 0, stream>>>(dst, counts, E);
    compute_dinv<<<(N + 255) / 256, 256, 0, stream>>>(counts, dinv, N);
    const int nb = (N + 255) / 256;
    scan1<<<nb, 256, 0, stream>>>(counts, scanned, btot, N);
    scan2<<<1, 256, 0, stream>>>(btot, nb);
    scan3<<<nb, 256, 0, stream>>>(scanned, btot, offs, cursor, N);
    fill_csr<<<(E + 255) / 256, 256, 0, stream>>>(src, dst, cursor, csr_src, E);

    const int mmb = (N + 63) / 64;
    const int emb = (E + EM_CHUNK - 1) / EM_CHUNK;

    unsigned char* hcur = Bh0;
    unsigned char* hnxt = Bh1;

    for (int t = 0; t < T; ++t) {
        if (t == 0) {
            // hs1 = (x @ W1) * dinv   (only timestep that uses W1)
            mfma_matmul<<<mmb, 256, 0, stream>>>(X0, T1, hcur, dinv, N);
        }
        // x2 = relu(agg(hs1)*dinv + b1); hs2 = (x2 @ W2) * dinv
        fused_gm<<<mmb, 256, 0, stream>>>(hcur, csr_src, offs, counts, dinv, b1,
                                          T2, 128, 0, Buv, hnxt, N);
        { unsigned char* tmp = hcur; hcur = hnxt; hnxt = tmp; }
        // x3' = relu(agg(hs2)*dinv + b2); hs3 = (x3' @ W3) * dinv
        fused_gm<<<mmb, 256, 0, stream>>>(hcur, csr_src, offs, counts, dinv, b2,
                                          T3, 128, 0, Buv, hnxt, N);
        { unsigned char* tmp = hcur; hcur = hnxt; hnxt = tmp; }
        // x3 = relu(agg(hs3)*dinv + b3); uv = x3 @ [We_u|We_v];
        // if not last timestep also hs1' = (x3 @ W2) * dinv  (W1:=W2 rebind)
        bool last = (t == T - 1);
        fused_gm<<<mmb, 256, 0, stream>>>(hcur, csr_src, offs, counts, dinv, b3,
                                          Tuv, last ? 256 : 384, 256, Buv, hnxt, N);
        if (!last) { unsigned char* tmp = hcur; hcur = hnxt; hnxt = tmp; }

        edge_mlp<<<emb, 256, 0, stream>>>(Buv, src, dst, ea + (size_t)t * E * 7,
                                          We + 256 * 128, be, Wg, acc + t, E);
    }
    write_out<<<1, 64, 0, stream>>>(acc, bg, (float*)d_out, 1.0f / (float)E, T);
}